// Round 1
// baseline (357.789 us; speedup 1.0000x reference)
//
#include <hip/hip_runtime.h>
#include <hip/hip_bf16.h>
#include <cstdint>
#include <cstddef>

using bf16 = __hip_bfloat16;
typedef __attribute__((ext_vector_type(8))) short short8;
typedef __attribute__((ext_vector_type(4))) float f32x4;

#define DEV static __device__ __forceinline__

// B=2, S=2048, D=768, H=12, DK=64, HID=3072, M = B*S = 4096
#define MROWS 4096
#define SEQ   2048
#define DMODEL 768
#define NHEAD 12
#define DHEAD 64
#define HID   3072

DEV void gload16(const void* g, void* l) {
  __builtin_amdgcn_global_load_lds((const __attribute__((address_space(1))) void*)g,
                                   (__attribute__((address_space(3))) void*)l, 16, 0, 0);
}

// ---------------- weight conversion ----------------
// WqkvT[2304][768]: row n = proj*768 + h*64 + k, col d. value = W{proj}[h][d][k]
__global__ __launch_bounds__(256) void cvt_qkv_k(const float* __restrict__ Wq,
                                                 const float* __restrict__ Wk,
                                                 const float* __restrict__ Wv,
                                                 bf16* __restrict__ out) {
  int idx = blockIdx.x * 256 + threadIdx.x;          // [0, 2304*768)
  int n = idx / DMODEL, d = idx - n * DMODEL;
  int proj = n / DMODEL;
  int within = n - proj * DMODEL;
  int hh = within >> 6, k = within & 63;
  const float* W = (proj == 0) ? Wq : (proj == 1 ? Wk : Wv);
  out[idx] = __float2bfloat16(W[((size_t)hh * DMODEL + d) * DHEAD + k]);
}

// W[R][C] row-major -> out[C][R] bf16 (out[c*R + r] = W[r*C + c])
__global__ __launch_bounds__(256) void cvt_t_k(const float* __restrict__ W,
                                               bf16* __restrict__ out, int R, int C) {
  int idx = blockIdx.x * 256 + threadIdx.x;          // [0, R*C)
  int c = idx / R, r = idx - c * R;
  out[idx] = __float2bfloat16(W[(size_t)r * C + c]);
}

// ---------------- layernorm (row of 768) ----------------
__global__ __launch_bounds__(256) void ln_k(const float* __restrict__ in,
                                            const float* __restrict__ gam,
                                            const float* __restrict__ bet,
                                            bf16* __restrict__ out) {
  int r = blockIdx.x;
  int tid = threadIdx.x;
  const float* p = in + (size_t)r * DMODEL;
  float v0 = p[tid], v1 = p[tid + 256], v2 = p[tid + 512];
  float s = v0 + v1 + v2;
  float ss = v0 * v0 + v1 * v1 + v2 * v2;
#pragma unroll
  for (int off = 1; off < 64; off <<= 1) {
    s += __shfl_xor(s, off);
    ss += __shfl_xor(ss, off);
  }
  __shared__ float rs[4], rss[4];
  int w = tid >> 6, l = tid & 63;
  if (l == 0) { rs[w] = s; rss[w] = ss; }
  __syncthreads();
  s = rs[0] + rs[1] + rs[2] + rs[3];
  ss = rss[0] + rss[1] + rss[2] + rss[3];
  float mean = s * (1.0f / 768.0f);
  float var = ss * (1.0f / 768.0f) - mean * mean;
  float inv = rsqrtf(var + 1e-5f);
  bf16* o = out + (size_t)r * DMODEL;
  o[tid]       = __float2bfloat16((v0 - mean) * inv * gam[tid] + bet[tid]);
  o[tid + 256] = __float2bfloat16((v1 - mean) * inv * gam[tid + 256] + bet[tid + 256]);
  o[tid + 512] = __float2bfloat16((v2 - mean) * inv * gam[tid + 512] + bet[tid + 512]);
}

// ---------------- GEMM: C[M][N] = A[M][K] * Bt[N][K]^T, 128x128 tile, BK=32 ----------------
// EPI 0: QKV  (n<1536 -> qk buf [m][1536], Q cols scaled 0.125; n>=1536 -> Vt[bh][dk][s])
// EPI 1: Wo   (of[m][768] = add[m][768] + acc)           fp32 out
// EPI 2: MLP1 (ob[m][3072] = bf16(gelu(acc + bias[n])))
// EPI 3: MLP2 (of[m][768] = add[m][768] + acc + bias[n]) fp32 out
template <int EPI>
__global__ __launch_bounds__(256) void gemm_bt(const bf16* __restrict__ A,
                                               const bf16* __restrict__ Bt, int K,
                                               bf16* __restrict__ ob,
                                               float* __restrict__ of,
                                               const float* __restrict__ add,
                                               const float* __restrict__ bias,
                                               bf16* __restrict__ vt) {
  __shared__ bf16 sA[128 * 32];
  __shared__ bf16 sB[128 * 32];
  const int tid = threadIdx.x;
  const int w = tid >> 6, l = tid & 63;
  const int lr = l & 15, lg = l >> 4;
  const int mbase = blockIdx.y * 128, nbase = blockIdx.x * 128;
  const int wm = (w >> 1) * 64, wn = (w & 1) * 64;

  f32x4 acc[4][4];
#pragma unroll
  for (int i = 0; i < 4; ++i)
#pragma unroll
    for (int j = 0; j < 4; ++j) acc[i][j] = (f32x4)0.0f;

  const int srow = l >> 2;            // 0..15
  const int scol = (l & 3) * 8;       // element offset
  const bf16* gA = A + (size_t)(mbase + w * 32 + srow) * K + scol;
  const bf16* gB = Bt + (size_t)(nbase + w * 32 + srow) * K + scol;
  bf16* lA = &sA[w * 1024];
  bf16* lB = &sB[w * 1024];

  const int nt = K >> 5;
  for (int t = 0; t < nt; ++t) {
    __syncthreads();
    const int k0 = t * 32;
    gload16(gA + k0, lA);
    gload16(gA + k0 + (size_t)16 * K, lA + 512);
    gload16(gB + k0, lB);
    gload16(gB + k0 + (size_t)16 * K, lB + 512);
    __syncthreads();
    short8 a[4], bb[4];
#pragma unroll
    for (int mi = 0; mi < 4; ++mi)
      a[mi] = *(const short8*)&sA[(wm + mi * 16 + lr) * 32 + lg * 8];
#pragma unroll
    for (int ni = 0; ni < 4; ++ni)
      bb[ni] = *(const short8*)&sB[(wn + ni * 16 + lr) * 32 + lg * 8];
#pragma unroll
    for (int mi = 0; mi < 4; ++mi)
#pragma unroll
      for (int ni = 0; ni < 4; ++ni)
        acc[mi][ni] = __builtin_amdgcn_mfma_f32_16x16x32_bf16(a[mi], bb[ni], acc[mi][ni], 0, 0, 0);
  }

  const int row0 = mbase + wm + lg * 4;
  const int col0 = nbase + wn + lr;
#pragma unroll
  for (int mi = 0; mi < 4; ++mi) {
#pragma unroll
    for (int ni = 0; ni < 4; ++ni) {
      const int c = col0 + ni * 16;
#pragma unroll
      for (int i = 0; i < 4; ++i) {
        const int r = row0 + mi * 16 + i;
        float v = acc[mi][ni][i];
        if constexpr (EPI == 0) {
          if (c < 1536) {
            float scv = (c < DMODEL) ? 0.125f : 1.0f;  // 1/sqrt(64) on Q
            ob[(size_t)r * 1536 + c] = __float2bfloat16(v * scv);
          } else {
            int within = c - 1536;
            int hh = within >> 6, kk = within & 63;
            int bidx = r >> 11, sq = r & 2047;
            vt[(((size_t)bidx * NHEAD + hh) * DHEAD + kk) * SEQ + sq] = __float2bfloat16(v);
          }
        } else if constexpr (EPI == 1) {
          of[(size_t)r * DMODEL + c] = add[(size_t)r * DMODEL + c] + v;
        } else if constexpr (EPI == 2) {
          float xx = v + bias[c];
          float ge = 0.5f * xx * (1.0f + erff(xx * 0.70710678118f));
          ob[(size_t)r * HID + c] = __float2bfloat16(ge);
        } else {
          of[(size_t)r * DMODEL + c] = add[(size_t)r * DMODEL + c] + v + bias[c];
        }
      }
    }
  }
}

// ---------------- flash attention (causal) ----------------
// qk: [4096][1536] bf16 (cols 0..767 = Q (pre-scaled), 768..1535 = K), per row b*2048+s
// vt: [24][64][2048] bf16 (V transposed per (b,h))
// o : [4096][768] bf16 (concat heads)
__global__ __launch_bounds__(256) void attn_k(const bf16* __restrict__ qk,
                                              const bf16* __restrict__ vt,
                                              bf16* __restrict__ o) {
  const int bh = blockIdx.y, b = bh / NHEAD, h = bh - b * NHEAD;
  const int qbase = blockIdx.x * 128;
  const int tid = threadIdx.x, w = tid >> 6, l = tid & 63;
  const int lr = l & 15, lg = l >> 4;
  __shared__ bf16 sK[64 * 64];       // [key][dk]
  __shared__ bf16 sV[64 * 64];       // [dk][key]
  __shared__ bf16 sP[128 * 72];      // [qrow][key], padded stride 72 (144B, 16B-aligned)

  // Q fragments in registers for the whole kernel
  short8 q[2][2];
#pragma unroll
  for (int mi = 0; mi < 2; ++mi)
#pragma unroll
    for (int kk = 0; kk < 2; ++kk) {
      int row = qbase + w * 32 + mi * 16 + lr;
      q[mi][kk] = *(const short8*)&qk[(size_t)(b * SEQ + row) * 1536 + h * DHEAD + kk * 32 + lg * 8];
    }

  f32x4 oa[2][4];
  float mst[2][4], lst[2][4];
#pragma unroll
  for (int mi = 0; mi < 2; ++mi)
#pragma unroll
    for (int i = 0; i < 4; ++i) {
      oa[mi][i] = (f32x4)0.0f;
      mst[mi][i] = -1e30f;
      lst[mi][i] = 0.0f;
    }

  const int srow = l >> 3;          // 0..7
  const int scol = (l & 7) * 8;     // element
  const bf16* gK = qk + (size_t)(b * SEQ + w * 16 + srow) * 1536 + DMODEL + h * DHEAD + scol;
  const bf16* gV = vt + ((size_t)bh * DHEAD + w * 16 + srow) * SEQ + scol;
  bf16* lK = &sK[w * 1024];
  bf16* lV = &sV[w * 1024];

  const int ktiles = 2 * blockIdx.x + 2;
  const int qmax = qbase + w * 32 + 31;   // wave-uniform causal bound
  for (int t = 0; t < ktiles; ++t) {
    const int kb = t * 64;
    __syncthreads();
    gload16(gK + (size_t)kb * 1536, lK);
    gload16(gK + (size_t)(kb + 8) * 1536, lK + 512);
    gload16(gV + kb, lV);
    gload16(gV + kb + (size_t)8 * SEQ, lV + 512);
    __syncthreads();
    if (kb > qmax) continue;   // fully masked for this wave (barriers already passed)

    // ---- S = Q K^T (rows of this wave: 32, keys: 64) ----
    short8 kf[4][2];
#pragma unroll
    for (int ni = 0; ni < 4; ++ni)
#pragma unroll
      for (int kk = 0; kk < 2; ++kk)
        kf[ni][kk] = *(const short8*)&sK[(ni * 16 + lr) * 64 + kk * 32 + lg * 8];
    f32x4 sc[2][4];
#pragma unroll
    for (int mi = 0; mi < 2; ++mi)
#pragma unroll
      for (int ni = 0; ni < 4; ++ni) {
        sc[mi][ni] = (f32x4)0.0f;
#pragma unroll
        for (int kk = 0; kk < 2; ++kk)
          sc[mi][ni] = __builtin_amdgcn_mfma_f32_16x16x32_bf16(q[mi][kk], kf[ni][kk], sc[mi][ni], 0, 0, 0);
      }

    // ---- mask + online softmax ----
    const int qrow0 = qbase + w * 32 + lg * 4;
#pragma unroll
    for (int mi = 0; mi < 2; ++mi)
#pragma unroll
      for (int i = 0; i < 4; ++i) {
        const int qg = qrow0 + mi * 16 + i;
        float tmax = -1e30f;
#pragma unroll
        for (int ni = 0; ni < 4; ++ni) {
          const int kg = kb + ni * 16 + lr;
          float v = sc[mi][ni][i];
          v = (kg > qg) ? -1e30f : v;
          sc[mi][ni][i] = v;
          tmax = fmaxf(tmax, v);
        }
#pragma unroll
        for (int off = 1; off < 16; off <<= 1) tmax = fmaxf(tmax, __shfl_xor(tmax, off));
        const float mn = fmaxf(mst[mi][i], tmax);
        const float scale = __expf(mst[mi][i] - mn);
        mst[mi][i] = mn;
        float rsum = 0.0f;
#pragma unroll
        for (int ni = 0; ni < 4; ++ni) {
          float pv = __expf(sc[mi][ni][i] - mn);
          sc[mi][ni][i] = pv;
          rsum += pv;
        }
#pragma unroll
        for (int off = 1; off < 16; off <<= 1) rsum += __shfl_xor(rsum, off);
        lst[mi][i] = lst[mi][i] * scale + rsum;
#pragma unroll
        for (int nk = 0; nk < 4; ++nk) oa[mi][nk][i] *= scale;
      }

    // ---- P to LDS (bf16), re-read in A-fragment layout ----
#pragma unroll
    for (int mi = 0; mi < 2; ++mi)
#pragma unroll
      for (int ni = 0; ni < 4; ++ni)
#pragma unroll
        for (int i = 0; i < 4; ++i)
          sP[(w * 32 + mi * 16 + lg * 4 + i) * 72 + ni * 16 + lr] = __float2bfloat16(sc[mi][ni][i]);
    asm volatile("s_waitcnt lgkmcnt(0)" ::: "memory");
    __builtin_amdgcn_sched_barrier(0);

#pragma unroll
    for (int mi = 0; mi < 2; ++mi) {
      short8 pf0 = *(const short8*)&sP[(w * 32 + mi * 16 + lr) * 72 + lg * 8];
      short8 pf1 = *(const short8*)&sP[(w * 32 + mi * 16 + lr) * 72 + 32 + lg * 8];
#pragma unroll
      for (int nk = 0; nk < 4; ++nk) {
        short8 vf0 = *(const short8*)&sV[(nk * 16 + lr) * 64 + lg * 8];
        short8 vf1 = *(const short8*)&sV[(nk * 16 + lr) * 64 + 32 + lg * 8];
        oa[mi][nk] = __builtin_amdgcn_mfma_f32_16x16x32_bf16(pf0, vf0, oa[mi][nk], 0, 0, 0);
        oa[mi][nk] = __builtin_amdgcn_mfma_f32_16x16x32_bf16(pf1, vf1, oa[mi][nk], 0, 0, 0);
      }
    }
  }

  // ---- epilogue: O / l ----
#pragma unroll
  for (int mi = 0; mi < 2; ++mi)
#pragma unroll
    for (int nk = 0; nk < 4; ++nk)
#pragma unroll
      for (int i = 0; i < 4; ++i) {
        int row = qbase + w * 32 + mi * 16 + lg * 4 + i;
        int col = h * DHEAD + nk * 16 + lr;
        o[(size_t)(b * SEQ + row) * DMODEL + col] = __float2bfloat16(oa[mi][nk][i] / lst[mi][i]);
      }
}

// ---------------- launch ----------------
extern "C" void kernel_launch(void* const* d_in, const int* in_sizes, int n_in,
                              void* d_out, int out_size, void* d_ws, size_t ws_size,
                              hipStream_t stream) {
  (void)in_sizes; (void)n_in; (void)out_size; (void)ws_size;
  const float* x   = (const float*)d_in[0];
  const float* Wq  = (const float*)d_in[1];
  const float* Wk  = (const float*)d_in[2];
  const float* Wv  = (const float*)d_in[3];
  const float* Wo  = (const float*)d_in[4];
  const float* W1  = (const float*)d_in[5];
  const float* b1  = (const float*)d_in[6];
  const float* W2  = (const float*)d_in[7];
  const float* b2  = (const float*)d_in[8];
  const float* g1  = (const float*)d_in[9];
  const float* be1 = (const float*)d_in[10];
  const float* g2  = (const float*)d_in[11];
  const float* be2 = (const float*)d_in[12];
  float* out = (float*)d_out;

  char* p = (char*)d_ws;
  bf16* WqkvT = (bf16*)p; p += (size_t)2304 * 768 * 2;
  bf16* WoT   = (bf16*)p; p += (size_t)768 * 768 * 2;
  bf16* W1T   = (bf16*)p; p += (size_t)3072 * 768 * 2;
  bf16* W2T   = (bf16*)p; p += (size_t)768 * 3072 * 2;
  bf16* h1    = (bf16*)p; p += (size_t)MROWS * DMODEL * 2;
  char* alias0 = p;                                   // U aliases QK+Vt+O (dead by then)
  bf16* QK    = (bf16*)p; p += (size_t)MROWS * 1536 * 2;
  bf16* Vt    = (bf16*)p; p += (size_t)24 * DHEAD * SEQ * 2;
  bf16* O     = (bf16*)p; p += (size_t)MROWS * DMODEL * 2;
  float* y    = (float*)p; p += (size_t)MROWS * DMODEL * 4;
  bf16* h2    = (bf16*)p; p += (size_t)MROWS * DMODEL * 2;
  bf16* U     = (bf16*)alias0;                        // [4096][3072] bf16 = 25.17MB, fits alias

  dim3 blk(256);
  cvt_qkv_k<<<(2304 * 768) / 256, blk, 0, stream>>>(Wq, Wk, Wv, WqkvT);
  cvt_t_k<<<(768 * 768) / 256, blk, 0, stream>>>(Wo, WoT, 768, 768);
  cvt_t_k<<<(768 * 3072) / 256, blk, 0, stream>>>(W1, W1T, 768, 3072);
  cvt_t_k<<<(3072 * 768) / 256, blk, 0, stream>>>(W2, W2T, 3072, 768);
  ln_k<<<MROWS, blk, 0, stream>>>(x, g1, be1, h1);
  gemm_bt<0><<<dim3(18, 32), blk, 0, stream>>>(h1, WqkvT, 768, QK, nullptr, nullptr, nullptr, Vt);
  attn_k<<<dim3(16, 24), blk, 0, stream>>>(QK, Vt, O);
  gemm_bt<1><<<dim3(6, 32), blk, 0, stream>>>(O, WoT, 768, nullptr, y, x, nullptr, nullptr);
  ln_k<<<MROWS, blk, 0, stream>>>(y, g2, be2, h2);
  gemm_bt<2><<<dim3(24, 32), blk, 0, stream>>>(h2, W1T, 768, U, nullptr, nullptr, b1, nullptr);
  gemm_bt<3><<<dim3(6, 32), blk, 0, stream>>>(U, W2T, 3072, nullptr, out, y, b2, nullptr);
}

// Round 2
// 295.768 us; speedup vs baseline: 1.2097x; 1.2097x over previous
//
#include <hip/hip_runtime.h>
#include <hip/hip_bf16.h>
#include <cstdint>
#include <cstddef>

using bf16 = __hip_bfloat16;
typedef __attribute__((ext_vector_type(8))) short short8;
typedef __attribute__((ext_vector_type(4))) float f32x4;

#define DEV static __device__ __forceinline__

// B=2, S=2048, D=768, H=12, DK=64, HID=3072, M = B*S = 4096
#define MROWS 4096
#define SEQ   2048
#define DMODEL 768
#define NHEAD 12
#define DHEAD 64
#define HID   3072

DEV void gload16(const void* g, void* l) {
  __builtin_amdgcn_global_load_lds((const __attribute__((address_space(1))) void*)g,
                                   (__attribute__((address_space(3))) void*)l, 16, 0, 0);
}

// ---------------- weight conversion ----------------
__global__ __launch_bounds__(256) void cvt_qkv_k(const float* __restrict__ Wq,
                                                 const float* __restrict__ Wk,
                                                 const float* __restrict__ Wv,
                                                 bf16* __restrict__ out) {
  int idx = blockIdx.x * 256 + threadIdx.x;          // [0, 2304*768)
  int n = idx / DMODEL, d = idx - n * DMODEL;
  int proj = n / DMODEL;
  int within = n - proj * DMODEL;
  int hh = within >> 6, k = within & 63;
  const float* W = (proj == 0) ? Wq : (proj == 1 ? Wk : Wv);
  out[idx] = __float2bfloat16(W[((size_t)hh * DMODEL + d) * DHEAD + k]);
}

// W[R][C] row-major -> out[C][R] bf16
__global__ __launch_bounds__(256) void cvt_t_k(const float* __restrict__ W,
                                               bf16* __restrict__ out, int R, int C) {
  int idx = blockIdx.x * 256 + threadIdx.x;
  int c = idx / R, r = idx - c * R;
  out[idx] = __float2bfloat16(W[(size_t)r * C + c]);
}

// ---------------- layernorm (row of 768) ----------------
__global__ __launch_bounds__(256) void ln_k(const float* __restrict__ in,
                                            const float* __restrict__ gam,
                                            const float* __restrict__ bet,
                                            bf16* __restrict__ out) {
  int r = blockIdx.x;
  int tid = threadIdx.x;
  const float* p = in + (size_t)r * DMODEL;
  float v0 = p[tid], v1 = p[tid + 256], v2 = p[tid + 512];
  float s = v0 + v1 + v2;
  float ss = v0 * v0 + v1 * v1 + v2 * v2;
#pragma unroll
  for (int off = 1; off < 64; off <<= 1) {
    s += __shfl_xor(s, off);
    ss += __shfl_xor(ss, off);
  }
  __shared__ float rs[4], rss[4];
  int w = tid >> 6, l = tid & 63;
  if (l == 0) { rs[w] = s; rss[w] = ss; }
  __syncthreads();
  s = rs[0] + rs[1] + rs[2] + rs[3];
  ss = rss[0] + rss[1] + rss[2] + rss[3];
  float mean = s * (1.0f / 768.0f);
  float var = ss * (1.0f / 768.0f) - mean * mean;
  float inv = rsqrtf(var + 1e-5f);
  bf16* o = out + (size_t)r * DMODEL;
  o[tid]       = __float2bfloat16((v0 - mean) * inv * gam[tid] + bet[tid]);
  o[tid + 256] = __float2bfloat16((v1 - mean) * inv * gam[tid + 256] + bet[tid + 256]);
  o[tid + 512] = __float2bfloat16((v2 - mean) * inv * gam[tid + 512] + bet[tid + 512]);
}

// ---------------- GEMM: C[M][N] = A[M][K] * Bt[N][K]^T, 128x128 tile, BK=32 ----------------
template <int EPI>
__global__ __launch_bounds__(256) void gemm_bt(const bf16* __restrict__ A,
                                               const bf16* __restrict__ Bt, int K,
                                               bf16* __restrict__ ob,
                                               float* __restrict__ of,
                                               const float* __restrict__ add,
                                               const float* __restrict__ bias,
                                               bf16* __restrict__ vt) {
  __shared__ bf16 sA[128 * 32];
  __shared__ bf16 sB[128 * 32];
  const int tid = threadIdx.x;
  const int w = tid >> 6, l = tid & 63;
  const int lr = l & 15, lg = l >> 4;
  const int mbase = blockIdx.y * 128, nbase = blockIdx.x * 128;
  const int wm = (w >> 1) * 64, wn = (w & 1) * 64;

  f32x4 acc[4][4];
#pragma unroll
  for (int i = 0; i < 4; ++i)
#pragma unroll
    for (int j = 0; j < 4; ++j) acc[i][j] = (f32x4)0.0f;

  const int srow = l >> 2;
  const int scol = (l & 3) * 8;
  const bf16* gA = A + (size_t)(mbase + w * 32 + srow) * K + scol;
  const bf16* gB = Bt + (size_t)(nbase + w * 32 + srow) * K + scol;
  bf16* lA = &sA[w * 1024];
  bf16* lB = &sB[w * 1024];

  const int nt = K >> 5;
  for (int t = 0; t < nt; ++t) {
    __syncthreads();
    const int k0 = t * 32;
    gload16(gA + k0, lA);
    gload16(gA + k0 + (size_t)16 * K, lA + 512);
    gload16(gB + k0, lB);
    gload16(gB + k0 + (size_t)16 * K, lB + 512);
    __syncthreads();
    short8 a[4], bb[4];
#pragma unroll
    for (int mi = 0; mi < 4; ++mi)
      a[mi] = *(const short8*)&sA[(wm + mi * 16 + lr) * 32 + lg * 8];
#pragma unroll
    for (int ni = 0; ni < 4; ++ni)
      bb[ni] = *(const short8*)&sB[(wn + ni * 16 + lr) * 32 + lg * 8];
#pragma unroll
    for (int mi = 0; mi < 4; ++mi)
#pragma unroll
      for (int ni = 0; ni < 4; ++ni)
        acc[mi][ni] = __builtin_amdgcn_mfma_f32_16x16x32_bf16(a[mi], bb[ni], acc[mi][ni], 0, 0, 0);
  }

  const int row0 = mbase + wm + lg * 4;
  const int col0 = nbase + wn + lr;
#pragma unroll
  for (int mi = 0; mi < 4; ++mi) {
#pragma unroll
    for (int ni = 0; ni < 4; ++ni) {
      const int c = col0 + ni * 16;
#pragma unroll
      for (int i = 0; i < 4; ++i) {
        const int r = row0 + mi * 16 + i;
        float v = acc[mi][ni][i];
        if constexpr (EPI == 0) {
          if (c < 1536) {
            float scv = (c < DMODEL) ? 0.125f : 1.0f;  // 1/sqrt(64) on Q
            ob[(size_t)r * 1536 + c] = __float2bfloat16(v * scv);
          } else {
            int within = c - 1536;
            int hh = within >> 6, kk = within & 63;
            int bidx = r >> 11, sq = r & 2047;
            vt[(((size_t)bidx * NHEAD + hh) * DHEAD + kk) * SEQ + sq] = __float2bfloat16(v);
          }
        } else if constexpr (EPI == 1) {
          of[(size_t)r * DMODEL + c] = add[(size_t)r * DMODEL + c] + v;
        } else if constexpr (EPI == 2) {
          float xx = v + bias[c];
          float ge = 0.5f * xx * (1.0f + erff(xx * 0.70710678118f));
          ob[(size_t)r * HID + c] = __float2bfloat16(ge);
        } else {
          of[(size_t)r * DMODEL + c] = add[(size_t)r * DMODEL + c] + v + bias[c];
        }
      }
    }
  }
}

// ---------------- flash attention (causal), v2 ----------------
// QBLK=64 (4 waves x 16 rows), KBLK=64, double-buffered K/V, XOR-swizzled LDS.
// qk: [4096][1536] bf16 (cols 0..767 = Q pre-scaled, 768..1535 = K)
// vt: [24][64][2048] bf16
// o : [4096][768] bf16
__global__ __launch_bounds__(256) void attn_k(const bf16* __restrict__ qk,
                                              const bf16* __restrict__ vt,
                                              bf16* __restrict__ o) {
  __shared__ bf16 sK[2][64 * 64];   // [key][dk], XOR-swizzled 16B columns
  __shared__ bf16 sV[2][64 * 64];   // [dk][key], XOR-swizzled
  __shared__ bf16 sP[64 * 64];      // [qrow][key], XOR-swizzled

  const int d = blockIdx.x;                 // 0..767
  const int bh = d % 24;
  const int rank = d / 24;                  // 0..31
  const int qt = (rank * 21) & 31;          // balance work across dispatch order
  const int b = bh / NHEAD, h = bh - b * NHEAD;
  const int qbase = qt * 64;
  const int tid = threadIdx.x, w = tid >> 6, l = tid & 63;
  const int lr = l & 15, lg = l >> 4;

  // ---- Q fragments (A-operand): row = qbase + w*16 + lr, k = kk*32 + lg*8 ----
  short8 q[2];
#pragma unroll
  for (int kk = 0; kk < 2; ++kk)
    q[kk] = *(const short8*)&qk[(size_t)(b * SEQ + qbase + w * 16 + lr) * 1536 + h * DHEAD + kk * 32 + lg * 8];

  f32x4 oa[4];
  float mst[4], lst[4];
#pragma unroll
  for (int i = 0; i < 4; ++i) { oa[i] = (f32x4)0.0f; mst[i] = -1e30f; lst[i] = 0.0f; }

  // ---- staging source (pre-swizzled 16B column so linear gload_lds dest = swizzled layout) ----
  const int srow3 = l >> 3;                 // row-within-8
  const int csrc = (l & 7) ^ srow3;         // logical 16B column this lane must fetch
  const bf16* gKb = qk + ((size_t)(b * SEQ) + w * 16 + srow3) * 1536 + DMODEL + h * DHEAD + csrc * 8;
  const bf16* gVb = vt + ((size_t)bh * DHEAD + w * 16 + srow3) * SEQ + csrc * 8;

  // ---- swizzled read offsets (elements). row&7 == lr&7 for all frag rows ----
  int rowb[4], cswz[2];
#pragma unroll
  for (int ni = 0; ni < 4; ++ni) rowb[ni] = (ni * 16 + lr) * 64;
#pragma unroll
  for (int kk = 0; kk < 2; ++kk) cswz[kk] = (((kk * 4 + lg) ^ (lr & 7)) << 3);
  const int prow = (w * 16 + lr) * 64;
  const int pswz0 = (lg * 8) ^ ((lr & 7) << 3);
  const int pswz1 = (32 + lg * 8) ^ ((lr & 7) << 3);

#define STAGE(buf, t)                                                              \
  {                                                                                \
    const int kb_ = (t) * 64;                                                      \
    gload16(gKb + (size_t)kb_ * 1536,        &sK[buf][(w * 16) * 64]);             \
    gload16(gKb + (size_t)(kb_ + 8) * 1536,  &sK[buf][(w * 16 + 8) * 64]);         \
    gload16(gVb + kb_,                       &sV[buf][(w * 16) * 64]);             \
    gload16(gVb + kb_ + (size_t)8 * SEQ,     &sV[buf][(w * 16 + 8) * 64]);         \
  }

  STAGE(0, 0);

  for (int t = 0; t <= qt; ++t) {
    const int cur = t & 1;
    const int kb = t * 64;
    if (t < qt) {
      STAGE(cur ^ 1, t + 1);
      asm volatile("s_waitcnt vmcnt(4)" ::: "memory");
    } else {
      asm volatile("s_waitcnt vmcnt(0)" ::: "memory");
    }
    __syncthreads();

    const bf16* sKc = sK[cur];
    const bf16* sVc = sV[cur];

    // ---- S = Q K^T : 16 q-rows x 64 keys ----
    f32x4 sc[4];
#pragma unroll
    for (int ni = 0; ni < 4; ++ni) {
      sc[ni] = (f32x4)0.0f;
#pragma unroll
      for (int kk = 0; kk < 2; ++kk) {
        short8 kf = *(const short8*)&sKc[rowb[ni] + cswz[kk]];
        sc[ni] = __builtin_amdgcn_mfma_f32_16x16x32_bf16(q[kk], kf, sc[ni], 0, 0, 0);
      }
    }

    // ---- mask + online softmax (row = qbase + w*16 + lg*4 + i, key = kb + ni*16 + lr) ----
    const int qrow0 = qbase + w * 16 + lg * 4;
#pragma unroll
    for (int i = 0; i < 4; ++i) {
      const int qg = qrow0 + i;
      float tmax = -1e30f;
#pragma unroll
      for (int ni = 0; ni < 4; ++ni) {
        const int kg = kb + ni * 16 + lr;
        float v = sc[ni][i];
        v = (kg > qg) ? -1e30f : v;
        sc[ni][i] = v;
        tmax = fmaxf(tmax, v);
      }
#pragma unroll
      for (int off = 1; off < 16; off <<= 1) tmax = fmaxf(tmax, __shfl_xor(tmax, off));
      const float mn = fmaxf(mst[i], tmax);
      const float scale = __expf(mst[i] - mn);
      mst[i] = mn;
      float rsum = 0.0f;
#pragma unroll
      for (int ni = 0; ni < 4; ++ni) {
        float pv = __expf(sc[ni][i] - mn);
        sc[ni][i] = pv;
        rsum += pv;
      }
#pragma unroll
      for (int off = 1; off < 16; off <<= 1) rsum += __shfl_xor(rsum, off);
      lst[i] = lst[i] * scale + rsum;
#pragma unroll
      for (int nk = 0; nk < 4; ++nk) oa[nk][i] *= scale;
    }

    // ---- P -> LDS (swizzled), re-read as A-fragment ----
#pragma unroll
    for (int ni = 0; ni < 4; ++ni)
#pragma unroll
      for (int i = 0; i < 4; ++i) {
        const int row = w * 16 + lg * 4 + i;
        const int col = ni * 16 + lr;
        sP[row * 64 + (col ^ ((row & 7) << 3))] = __float2bfloat16(sc[ni][i]);
      }
    asm volatile("s_waitcnt lgkmcnt(0)" ::: "memory");
    __builtin_amdgcn_sched_barrier(0);

    short8 pf0 = *(const short8*)&sP[prow + pswz0];
    short8 pf1 = *(const short8*)&sP[prow + pswz1];
#pragma unroll
    for (int nk = 0; nk < 4; ++nk) {
      short8 vf0 = *(const short8*)&sVc[rowb[nk] + cswz[0]];
      short8 vf1 = *(const short8*)&sVc[rowb[nk] + cswz[1]];
      oa[nk] = __builtin_amdgcn_mfma_f32_16x16x32_bf16(pf0, vf0, oa[nk], 0, 0, 0);
      oa[nk] = __builtin_amdgcn_mfma_f32_16x16x32_bf16(pf1, vf1, oa[nk], 0, 0, 0);
    }
    __syncthreads();
  }
#undef STAGE

  // ---- epilogue: O / l ----
#pragma unroll
  for (int nk = 0; nk < 4; ++nk)
#pragma unroll
    for (int i = 0; i < 4; ++i) {
      int row = qbase + w * 16 + lg * 4 + i;
      int col = h * DHEAD + nk * 16 + lr;
      o[(size_t)(b * SEQ + row) * DMODEL + col] = __float2bfloat16(oa[nk][i] / lst[i]);
    }
}

// ---------------- launch ----------------
extern "C" void kernel_launch(void* const* d_in, const int* in_sizes, int n_in,
                              void* d_out, int out_size, void* d_ws, size_t ws_size,
                              hipStream_t stream) {
  (void)in_sizes; (void)n_in; (void)out_size; (void)ws_size;
  const float* x   = (const float*)d_in[0];
  const float* Wq  = (const float*)d_in[1];
  const float* Wk  = (const float*)d_in[2];
  const float* Wv  = (const float*)d_in[3];
  const float* Wo  = (const float*)d_in[4];
  const float* W1  = (const float*)d_in[5];
  const float* b1  = (const float*)d_in[6];
  const float* W2  = (const float*)d_in[7];
  const float* b2  = (const float*)d_in[8];
  const float* g1  = (const float*)d_in[9];
  const float* be1 = (const float*)d_in[10];
  const float* g2  = (const float*)d_in[11];
  const float* be2 = (const float*)d_in[12];
  float* out = (float*)d_out;

  char* p = (char*)d_ws;
  bf16* WqkvT = (bf16*)p; p += (size_t)2304 * 768 * 2;
  bf16* WoT   = (bf16*)p; p += (size_t)768 * 768 * 2;
  bf16* W1T   = (bf16*)p; p += (size_t)3072 * 768 * 2;
  bf16* W2T   = (bf16*)p; p += (size_t)768 * 3072 * 2;
  bf16* h1    = (bf16*)p; p += (size_t)MROWS * DMODEL * 2;
  char* alias0 = p;                                   // U aliases QK+Vt+O (dead by then)
  bf16* QK    = (bf16*)p; p += (size_t)MROWS * 1536 * 2;
  bf16* Vt    = (bf16*)p; p += (size_t)24 * DHEAD * SEQ * 2;
  bf16* O     = (bf16*)p; p += (size_t)MROWS * DMODEL * 2;
  float* y    = (float*)p; p += (size_t)MROWS * DMODEL * 4;
  bf16* h2    = (bf16*)p; p += (size_t)MROWS * DMODEL * 2;
  bf16* U     = (bf16*)alias0;                        // [4096][3072] bf16

  dim3 blk(256);
  cvt_qkv_k<<<(2304 * 768) / 256, blk, 0, stream>>>(Wq, Wk, Wv, WqkvT);
  cvt_t_k<<<(768 * 768) / 256, blk, 0, stream>>>(Wo, WoT, 768, 768);
  cvt_t_k<<<(768 * 3072) / 256, blk, 0, stream>>>(W1, W1T, 768, 3072);
  cvt_t_k<<<(3072 * 768) / 256, blk, 0, stream>>>(W2, W2T, 3072, 768);
  ln_k<<<MROWS, blk, 0, stream>>>(x, g1, be1, h1);
  gemm_bt<0><<<dim3(18, 32), blk, 0, stream>>>(h1, WqkvT, 768, QK, nullptr, nullptr, nullptr, Vt);
  attn_k<<<768, blk, 0, stream>>>(QK, Vt, O);
  gemm_bt<1><<<dim3(6, 32), blk, 0, stream>>>(O, WoT, 768, nullptr, y, x, nullptr, nullptr);
  ln_k<<<MROWS, blk, 0, stream>>>(y, g2, be2, h2);
  gemm_bt<2><<<dim3(24, 32), blk, 0, stream>>>(h2, W1T, 768, U, nullptr, nullptr, b1, nullptr);
  gemm_bt<3><<<dim3(6, 32), blk, 0, stream>>>(U, W2T, 3072, nullptr, out, y, b2, nullptr);
}

// Round 3
// 268.716 us; speedup vs baseline: 1.3315x; 1.1007x over previous
//
#include <hip/hip_runtime.h>
#include <hip/hip_bf16.h>
#include <cstdint>
#include <cstddef>

using bf16 = __hip_bfloat16;
typedef __attribute__((ext_vector_type(8))) short short8;
typedef __attribute__((ext_vector_type(4))) float f32x4;

#define DEV static __device__ __forceinline__

// B=2, S=2048, D=768, H=12, DK=64, HID=3072, M = B*S = 4096
#define MROWS 4096
#define SEQ   2048
#define DMODEL 768
#define NHEAD 12
#define DHEAD 64
#define HID   3072

DEV void gload16(const void* g, void* l) {
  __builtin_amdgcn_global_load_lds((const __attribute__((address_space(1))) void*)g,
                                   (__attribute__((address_space(3))) void*)l, 16, 0, 0);
}

// ---------------- weight conversion ----------------
__global__ __launch_bounds__(256) void cvt_qkv_k(const float* __restrict__ Wq,
                                                 const float* __restrict__ Wk,
                                                 const float* __restrict__ Wv,
                                                 bf16* __restrict__ out) {
  int idx = blockIdx.x * 256 + threadIdx.x;          // [0, 2304*768)
  int n = idx / DMODEL, d = idx - n * DMODEL;
  int proj = n / DMODEL;
  int within = n - proj * DMODEL;
  int hh = within >> 6, k = within & 63;
  const float* W = (proj == 0) ? Wq : (proj == 1 ? Wk : Wv);
  out[idx] = __float2bfloat16(W[((size_t)hh * DMODEL + d) * DHEAD + k]);
}

// W[R][C] row-major -> out[C][R] bf16
__global__ __launch_bounds__(256) void cvt_t_k(const float* __restrict__ W,
                                               bf16* __restrict__ out, int R, int C) {
  int idx = blockIdx.x * 256 + threadIdx.x;
  int c = idx / R, r = idx - c * R;
  out[idx] = __float2bfloat16(W[(size_t)r * C + c]);
}

// ---------------- layernorm (row of 768) ----------------
__global__ __launch_bounds__(256) void ln_k(const float* __restrict__ in,
                                            const float* __restrict__ gam,
                                            const float* __restrict__ bet,
                                            bf16* __restrict__ out) {
  int r = blockIdx.x;
  int tid = threadIdx.x;
  const float* p = in + (size_t)r * DMODEL;
  float v0 = p[tid], v1 = p[tid + 256], v2 = p[tid + 512];
  float s = v0 + v1 + v2;
  float ss = v0 * v0 + v1 * v1 + v2 * v2;
#pragma unroll
  for (int off = 1; off < 64; off <<= 1) {
    s += __shfl_xor(s, off);
    ss += __shfl_xor(ss, off);
  }
  __shared__ float rs[4], rss[4];
  int w = tid >> 6, l = tid & 63;
  if (l == 0) { rs[w] = s; rss[w] = ss; }
  __syncthreads();
  s = rs[0] + rs[1] + rs[2] + rs[3];
  ss = rss[0] + rss[1] + rss[2] + rss[3];
  float mean = s * (1.0f / 768.0f);
  float var = ss * (1.0f / 768.0f) - mean * mean;
  float inv = rsqrtf(var + 1e-5f);
  bf16* o = out + (size_t)r * DMODEL;
  o[tid]       = __float2bfloat16((v0 - mean) * inv * gam[tid] + bet[tid]);
  o[tid + 256] = __float2bfloat16((v1 - mean) * inv * gam[tid + 256] + bet[tid + 256]);
  o[tid + 512] = __float2bfloat16((v2 - mean) * inv * gam[tid + 512] + bet[tid + 512]);
}

// ---------------- GEMM: C[M][N] = A[M][K] * Bt[N][K]^T ----------------
// Tile 128 x BN (BN = 128 or 64), BK=32, double-buffered LDS, counted vmcnt,
// raw barriers (no implicit vmcnt(0) drain).
template <int EPI, int BN>
__global__ __launch_bounds__(256) void gemm_bt(const bf16* __restrict__ A,
                                               const bf16* __restrict__ Bt, int K,
                                               bf16* __restrict__ ob,
                                               float* __restrict__ of,
                                               const float* __restrict__ add,
                                               const float* __restrict__ bias,
                                               bf16* __restrict__ vt) {
  __shared__ bf16 sA[2][128 * 32];
  __shared__ bf16 sB[2][BN * 32];
  constexpr int NI = BN / 32;                  // 4 or 2 output frags in N per wave
  const int tid = threadIdx.x;
  const int w = tid >> 6, l = tid & 63;
  const int lr = l & 15, lg = l >> 4;
  const int mbase = blockIdx.y * 128, nbase = blockIdx.x * BN;
  const int wm = (w >> 1) * 64, wn = (w & 1) * (BN / 2);

  f32x4 acc[4][NI];
#pragma unroll
  for (int i = 0; i < 4; ++i)
#pragma unroll
    for (int j = 0; j < NI; ++j) acc[i][j] = (f32x4)0.0f;

  const int srow = l >> 2;
  const int scol = (l & 3) * 8;
  const bf16* gA = A + (size_t)(mbase + w * 32 + srow) * K + scol;
  const bf16* gB = Bt + (size_t)(nbase + (BN == 128 ? w * 32 : w * 16) + srow) * K + scol;

#define GSTAGE(bufi, t)                                                      \
  {                                                                          \
    const int k0_ = (t) * 32;                                                \
    gload16(gA + k0_, &sA[bufi][w * 1024]);                                  \
    gload16(gA + k0_ + (size_t)16 * K, &sA[bufi][w * 1024 + 512]);           \
    if constexpr (BN == 128) {                                               \
      gload16(gB + k0_, &sB[bufi][w * 1024]);                                \
      gload16(gB + k0_ + (size_t)16 * K, &sB[bufi][w * 1024 + 512]);         \
    } else {                                                                 \
      gload16(gB + k0_, &sB[bufi][w * 512]);                                 \
    }                                                                        \
  }

  const int nt = K >> 5;
  GSTAGE(0, 0);
  for (int t = 0; t < nt; ++t) {
    const int cur = t & 1;
    if (t + 1 < nt) {
      GSTAGE(cur ^ 1, t + 1);
      if constexpr (BN == 128) asm volatile("s_waitcnt vmcnt(4)" ::: "memory");
      else                     asm volatile("s_waitcnt vmcnt(3)" ::: "memory");
    } else {
      asm volatile("s_waitcnt vmcnt(0)" ::: "memory");
    }
    __builtin_amdgcn_s_barrier();        // buf[cur] complete for all waves
    __builtin_amdgcn_sched_barrier(0);

    short8 a[4], bb[NI];
#pragma unroll
    for (int mi = 0; mi < 4; ++mi)
      a[mi] = *(const short8*)&sA[cur][(wm + mi * 16 + lr) * 32 + lg * 8];
#pragma unroll
    for (int ni = 0; ni < NI; ++ni)
      bb[ni] = *(const short8*)&sB[cur][(wn + ni * 16 + lr) * 32 + lg * 8];
#pragma unroll
    for (int mi = 0; mi < 4; ++mi)
#pragma unroll
      for (int ni = 0; ni < NI; ++ni)
        acc[mi][ni] = __builtin_amdgcn_mfma_f32_16x16x32_bf16(a[mi], bb[ni], acc[mi][ni], 0, 0, 0);

    __builtin_amdgcn_s_barrier();        // all waves done reading buf[cur]
    __builtin_amdgcn_sched_barrier(0);
  }
#undef GSTAGE

  const int row0 = mbase + wm + lg * 4;
  const int col0 = nbase + wn + lr;
#pragma unroll
  for (int mi = 0; mi < 4; ++mi) {
#pragma unroll
    for (int ni = 0; ni < NI; ++ni) {
      const int c = col0 + ni * 16;
#pragma unroll
      for (int i = 0; i < 4; ++i) {
        const int r = row0 + mi * 16 + i;
        float v = acc[mi][ni][i];
        if constexpr (EPI == 0) {
          if (c < 1536) {
            float scv = (c < DMODEL) ? 0.125f : 1.0f;  // 1/sqrt(64) on Q
            ob[(size_t)r * 1536 + c] = __float2bfloat16(v * scv);
          } else {
            int within = c - 1536;
            int hh = within >> 6, kk = within & 63;
            int bidx = r >> 11, sq = r & 2047;
            vt[(((size_t)bidx * NHEAD + hh) * DHEAD + kk) * SEQ + sq] = __float2bfloat16(v);
          }
        } else if constexpr (EPI == 1) {
          of[(size_t)r * DMODEL + c] = add[(size_t)r * DMODEL + c] + v;
        } else if constexpr (EPI == 2) {
          float xx = v + bias[c];
          float ge = 0.5f * xx * (1.0f + erff(xx * 0.70710678118f));
          ob[(size_t)r * HID + c] = __float2bfloat16(ge);
        } else {
          of[(size_t)r * DMODEL + c] = add[(size_t)r * DMODEL + c] + v + bias[c];
        }
      }
    }
  }
}

// ---------------- flash attention (causal) ----------------
// QBLK=64 (4 waves x 16 rows), KBLK=64, double-buffered K/V, XOR-swizzled LDS,
// counted vmcnt + raw barriers.
__global__ __launch_bounds__(256) void attn_k(const bf16* __restrict__ qk,
                                              const bf16* __restrict__ vt,
                                              bf16* __restrict__ o) {
  __shared__ bf16 sK[2][64 * 64];   // [key][dk], XOR-swizzled 16B columns
  __shared__ bf16 sV[2][64 * 64];   // [dk][key], XOR-swizzled
  __shared__ bf16 sP[64 * 64];      // [qrow][key], XOR-swizzled, wave-private rows

  const int d = blockIdx.x;                 // 0..767
  const int bh = d % 24;
  const int rank = d / 24;                  // 0..31
  const int qt = (rank * 21) & 31;          // balance work across dispatch order
  const int b = bh / NHEAD, h = bh - b * NHEAD;
  const int qbase = qt * 64;
  const int tid = threadIdx.x, w = tid >> 6, l = tid & 63;
  const int lr = l & 15, lg = l >> 4;

  short8 q[2];
#pragma unroll
  for (int kk = 0; kk < 2; ++kk)
    q[kk] = *(const short8*)&qk[(size_t)(b * SEQ + qbase + w * 16 + lr) * 1536 + h * DHEAD + kk * 32 + lg * 8];

  f32x4 oa[4];
  float mst[4], lst[4];
#pragma unroll
  for (int i = 0; i < 4; ++i) { oa[i] = (f32x4)0.0f; mst[i] = -1e30f; lst[i] = 0.0f; }

  const int srow3 = l >> 3;
  const int csrc = (l & 7) ^ srow3;         // pre-swizzled 16B column (both-sides rule)
  const bf16* gKb = qk + ((size_t)(b * SEQ) + w * 16 + srow3) * 1536 + DMODEL + h * DHEAD + csrc * 8;
  const bf16* gVb = vt + ((size_t)bh * DHEAD + w * 16 + srow3) * SEQ + csrc * 8;

  int rowb[4], cswz[2];
#pragma unroll
  for (int ni = 0; ni < 4; ++ni) rowb[ni] = (ni * 16 + lr) * 64;
#pragma unroll
  for (int kk = 0; kk < 2; ++kk) cswz[kk] = (((kk * 4 + lg) ^ (lr & 7)) << 3);
  const int prow = (w * 16 + lr) * 64;
  const int pswz0 = (lg * 8) ^ ((lr & 7) << 3);
  const int pswz1 = (32 + lg * 8) ^ ((lr & 7) << 3);

#define STAGE(buf, t)                                                              \
  {                                                                                \
    const int kb_ = (t) * 64;                                                      \
    gload16(gKb + (size_t)kb_ * 1536,        &sK[buf][(w * 16) * 64]);             \
    gload16(gKb + (size_t)(kb_ + 8) * 1536,  &sK[buf][(w * 16 + 8) * 64]);         \
    gload16(gVb + kb_,                       &sV[buf][(w * 16) * 64]);             \
    gload16(gVb + kb_ + (size_t)8 * SEQ,     &sV[buf][(w * 16 + 8) * 64]);         \
  }

  STAGE(0, 0);

  for (int t = 0; t <= qt; ++t) {
    const int cur = t & 1;
    const int kb = t * 64;
    if (t < qt) {
      STAGE(cur ^ 1, t + 1);
      asm volatile("s_waitcnt vmcnt(4)" ::: "memory");
    } else {
      asm volatile("s_waitcnt vmcnt(0)" ::: "memory");
    }
    __builtin_amdgcn_s_barrier();
    __builtin_amdgcn_sched_barrier(0);

    const bf16* sKc = sK[cur];
    const bf16* sVc = sV[cur];

    // ---- S = Q K^T ----
    f32x4 sc[4];
#pragma unroll
    for (int ni = 0; ni < 4; ++ni) {
      sc[ni] = (f32x4)0.0f;
#pragma unroll
      for (int kk = 0; kk < 2; ++kk) {
        short8 kf = *(const short8*)&sKc[rowb[ni] + cswz[kk]];
        sc[ni] = __builtin_amdgcn_mfma_f32_16x16x32_bf16(q[kk], kf, sc[ni], 0, 0, 0);
      }
    }

    // ---- mask + online softmax ----
    const int qrow0 = qbase + w * 16 + lg * 4;
#pragma unroll
    for (int i = 0; i < 4; ++i) {
      const int qg = qrow0 + i;
      float tmax = -1e30f;
#pragma unroll
      for (int ni = 0; ni < 4; ++ni) {
        const int kg = kb + ni * 16 + lr;
        float v = sc[ni][i];
        v = (kg > qg) ? -1e30f : v;
        sc[ni][i] = v;
        tmax = fmaxf(tmax, v);
      }
#pragma unroll
      for (int off = 1; off < 16; off <<= 1) tmax = fmaxf(tmax, __shfl_xor(tmax, off));
      const float mn = fmaxf(mst[i], tmax);
      const float scale = __expf(mst[i] - mn);
      mst[i] = mn;
      float rsum = 0.0f;
#pragma unroll
      for (int ni = 0; ni < 4; ++ni) {
        float pv = __expf(sc[ni][i] - mn);
        sc[ni][i] = pv;
        rsum += pv;
      }
#pragma unroll
      for (int off = 1; off < 16; off <<= 1) rsum += __shfl_xor(rsum, off);
      lst[i] = lst[i] * scale + rsum;
#pragma unroll
      for (int nk = 0; nk < 4; ++nk) oa[nk][i] *= scale;
    }

    // ---- P -> LDS (swizzled, wave-private rows), re-read as A-fragment ----
#pragma unroll
    for (int ni = 0; ni < 4; ++ni)
#pragma unroll
      for (int i = 0; i < 4; ++i) {
        const int row = w * 16 + lg * 4 + i;
        const int col = ni * 16 + lr;
        sP[row * 64 + (col ^ ((row & 7) << 3))] = __float2bfloat16(sc[ni][i]);
      }
    asm volatile("s_waitcnt lgkmcnt(0)" ::: "memory");
    __builtin_amdgcn_sched_barrier(0);

    short8 pf0 = *(const short8*)&sP[prow + pswz0];
    short8 pf1 = *(const short8*)&sP[prow + pswz1];
#pragma unroll
    for (int nk = 0; nk < 4; ++nk) {
      short8 vf0 = *(const short8*)&sVc[rowb[nk] + cswz[0]];
      short8 vf1 = *(const short8*)&sVc[rowb[nk] + cswz[1]];
      oa[nk] = __builtin_amdgcn_mfma_f32_16x16x32_bf16(pf0, vf0, oa[nk], 0, 0, 0);
      oa[nk] = __builtin_amdgcn_mfma_f32_16x16x32_bf16(pf1, vf1, oa[nk], 0, 0, 0);
    }
    __builtin_amdgcn_s_barrier();
    __builtin_amdgcn_sched_barrier(0);
  }
#undef STAGE

  // ---- epilogue: O / l ----
#pragma unroll
  for (int nk = 0; nk < 4; ++nk)
#pragma unroll
    for (int i = 0; i < 4; ++i) {
      int row = qbase + w * 16 + lg * 4 + i;
      int col = h * DHEAD + nk * 16 + lr;
      o[(size_t)(b * SEQ + row) * DMODEL + col] = __float2bfloat16(oa[nk][i] / lst[i]);
    }
}

// ---------------- launch ----------------
extern "C" void kernel_launch(void* const* d_in, const int* in_sizes, int n_in,
                              void* d_out, int out_size, void* d_ws, size_t ws_size,
                              hipStream_t stream) {
  (void)in_sizes; (void)n_in; (void)out_size; (void)ws_size;
  const float* x   = (const float*)d_in[0];
  const float* Wq  = (const float*)d_in[1];
  const float* Wk  = (const float*)d_in[2];
  const float* Wv  = (const float*)d_in[3];
  const float* Wo  = (const float*)d_in[4];
  const float* W1  = (const float*)d_in[5];
  const float* b1  = (const float*)d_in[6];
  const float* W2  = (const float*)d_in[7];
  const float* b2  = (const float*)d_in[8];
  const float* g1  = (const float*)d_in[9];
  const float* be1 = (const float*)d_in[10];
  const float* g2  = (const float*)d_in[11];
  const float* be2 = (const float*)d_in[12];
  float* out = (float*)d_out;

  char* p = (char*)d_ws;
  bf16* WqkvT = (bf16*)p; p += (size_t)2304 * 768 * 2;
  bf16* WoT   = (bf16*)p; p += (size_t)768 * 768 * 2;
  bf16* W1T   = (bf16*)p; p += (size_t)3072 * 768 * 2;
  bf16* W2T   = (bf16*)p; p += (size_t)768 * 3072 * 2;
  bf16* h1    = (bf16*)p; p += (size_t)MROWS * DMODEL * 2;
  char* alias0 = p;                                   // U aliases QK+Vt+O (dead by then)
  bf16* QK    = (bf16*)p; p += (size_t)MROWS * 1536 * 2;
  bf16* Vt    = (bf16*)p; p += (size_t)24 * DHEAD * SEQ * 2;
  bf16* O     = (bf16*)p; p += (size_t)MROWS * DMODEL * 2;
  float* y    = (float*)p; p += (size_t)MROWS * DMODEL * 4;
  bf16* h2    = (bf16*)p; p += (size_t)MROWS * DMODEL * 2;
  bf16* U     = (bf16*)alias0;                        // [4096][3072] bf16

  dim3 blk(256);
  cvt_qkv_k<<<(2304 * 768) / 256, blk, 0, stream>>>(Wq, Wk, Wv, WqkvT);
  cvt_t_k<<<(768 * 768) / 256, blk, 0, stream>>>(Wo, WoT, 768, 768);
  cvt_t_k<<<(768 * 3072) / 256, blk, 0, stream>>>(W1, W1T, 768, 3072);
  cvt_t_k<<<(3072 * 768) / 256, blk, 0, stream>>>(W2, W2T, 3072, 768);
  ln_k<<<MROWS, blk, 0, stream>>>(x, g1, be1, h1);
  gemm_bt<0, 128><<<dim3(18, 32), blk, 0, stream>>>(h1, WqkvT, 768, QK, nullptr, nullptr, nullptr, Vt);
  attn_k<<<768, blk, 0, stream>>>(QK, Vt, O);
  gemm_bt<1, 64><<<dim3(12, 32), blk, 0, stream>>>(O, WoT, 768, nullptr, y, x, nullptr, nullptr);
  ln_k<<<MROWS, blk, 0, stream>>>(y, g2, be2, h2);
  gemm_bt<2, 128><<<dim3(24, 32), blk, 0, stream>>>(h2, W1T, 768, U, nullptr, nullptr, b1, nullptr);
  gemm_bt<3, 64><<<dim3(12, 32), blk, 0, stream>>>(U, W2T, 3072, nullptr, out, y, b2, nullptr);
}

// Round 4
// 258.484 us; speedup vs baseline: 1.3842x; 1.0396x over previous
//
#include <hip/hip_runtime.h>
#include <hip/hip_bf16.h>
#include <cstdint>
#include <cstddef>

using bf16 = __hip_bfloat16;
typedef __attribute__((ext_vector_type(8))) short short8;
typedef __attribute__((ext_vector_type(4))) float f32x4;
typedef __attribute__((ext_vector_type(2))) int i32x2;

#define DEV static __device__ __forceinline__

// B=2, S=2048, D=768, H=12, DK=64, HID=3072, M = B*S = 4096
#define MROWS 4096
#define SEQ   2048
#define DMODEL 768
#define NHEAD 12
#define DHEAD 64
#define HID   3072
// 0.125 * log2(e): QK^T lands in exp2 domain
#define QSCALE 0.1803368801111204f

DEV void gload16(const void* g, void* l) {
  __builtin_amdgcn_global_load_lds((const __attribute__((address_space(1))) void*)g,
                                   (__attribute__((address_space(3))) void*)l, 16, 0, 0);
}

template <int CTRL>
DEV float dppf(float x) {
  return __builtin_bit_cast(float,
      __builtin_amdgcn_mov_dpp(__builtin_bit_cast(int, x), CTRL, 0xF, 0xF, true));
}
// all-reduce over the 16 lanes of a DPP row (our lr dimension)
DEV float red_max16(float x) {
  x = fmaxf(x, dppf<0xB1>(x));   // quad_perm [1,0,3,2]
  x = fmaxf(x, dppf<0x4E>(x));   // quad_perm [2,3,0,1]
  x = fmaxf(x, dppf<0x141>(x));  // row_half_mirror
  x = fmaxf(x, dppf<0x140>(x));  // row_mirror
  return x;
}
DEV float red_add16(float x) {
  x += dppf<0xB1>(x);
  x += dppf<0x4E>(x);
  x += dppf<0x141>(x);
  x += dppf<0x140>(x);
  return x;
}

// ---------------- weight conversion ----------------
__global__ __launch_bounds__(256) void cvt_qkv_k(const float* __restrict__ Wq,
                                                 const float* __restrict__ Wk,
                                                 const float* __restrict__ Wv,
                                                 bf16* __restrict__ out) {
  int idx = blockIdx.x * 256 + threadIdx.x;          // [0, 2304*768)
  int n = idx / DMODEL, d = idx - n * DMODEL;
  int proj = n / DMODEL;
  int within = n - proj * DMODEL;
  int hh = within >> 6, k = within & 63;
  const float* W = (proj == 0) ? Wq : (proj == 1 ? Wk : Wv);
  out[idx] = __float2bfloat16(W[((size_t)hh * DMODEL + d) * DHEAD + k]);
}

// W[R][C] row-major -> out[C][R] bf16
__global__ __launch_bounds__(256) void cvt_t_k(const float* __restrict__ W,
                                               bf16* __restrict__ out, int R, int C) {
  int idx = blockIdx.x * 256 + threadIdx.x;
  int c = idx / R, r = idx - c * R;
  out[idx] = __float2bfloat16(W[(size_t)r * C + c]);
}

// ---------------- layernorm (row of 768) ----------------
__global__ __launch_bounds__(256) void ln_k(const float* __restrict__ in,
                                            const float* __restrict__ gam,
                                            const float* __restrict__ bet,
                                            bf16* __restrict__ out) {
  int r = blockIdx.x;
  int tid = threadIdx.x;
  const float* p = in + (size_t)r * DMODEL;
  float v0 = p[tid], v1 = p[tid + 256], v2 = p[tid + 512];
  float s = v0 + v1 + v2;
  float ss = v0 * v0 + v1 * v1 + v2 * v2;
#pragma unroll
  for (int off = 1; off < 64; off <<= 1) {
    s += __shfl_xor(s, off);
    ss += __shfl_xor(ss, off);
  }
  __shared__ float rs[4], rss[4];
  int w = tid >> 6, l = tid & 63;
  if (l == 0) { rs[w] = s; rss[w] = ss; }
  __syncthreads();
  s = rs[0] + rs[1] + rs[2] + rs[3];
  ss = rss[0] + rss[1] + rss[2] + rss[3];
  float mean = s * (1.0f / 768.0f);
  float var = ss * (1.0f / 768.0f) - mean * mean;
  float inv = rsqrtf(var + 1e-5f);
  bf16* o = out + (size_t)r * DMODEL;
  o[tid]       = __float2bfloat16((v0 - mean) * inv * gam[tid] + bet[tid]);
  o[tid + 256] = __float2bfloat16((v1 - mean) * inv * gam[tid + 256] + bet[tid + 256]);
  o[tid + 512] = __float2bfloat16((v2 - mean) * inv * gam[tid + 512] + bet[tid + 512]);
}

// ---------------- GEMM: C[M][N] = A[M][K] * Bt[N][K]^T ----------------
// Tile BM x BN, BK=32, double-buffered LDS, counted vmcnt, raw barriers.
template <int EPI, int BM, int BN>
__global__ __launch_bounds__(256) void gemm_bt(const bf16* __restrict__ A,
                                               const bf16* __restrict__ Bt, int K,
                                               bf16* __restrict__ ob,
                                               float* __restrict__ of,
                                               const float* __restrict__ add,
                                               const float* __restrict__ bias,
                                               bf16* __restrict__ vt) {
  __shared__ bf16 sA[2][BM * 32];
  __shared__ bf16 sB[2][BN * 32];
  constexpr int MI = BM / 32;
  constexpr int NI = BN / 32;
  constexpr int LOADS = (BM == 128 ? 2 : 1) + (BN == 128 ? 2 : 1);
  const int tid = threadIdx.x;
  const int w = tid >> 6, l = tid & 63;
  const int lr = l & 15, lg = l >> 4;
  const int mbase = blockIdx.y * BM, nbase = blockIdx.x * BN;
  const int wm = (w >> 1) * (BM / 2), wn = (w & 1) * (BN / 2);

  f32x4 acc[MI][NI];
#pragma unroll
  for (int i = 0; i < MI; ++i)
#pragma unroll
    for (int j = 0; j < NI; ++j) acc[i][j] = (f32x4)0.0f;

  const int srow = l >> 2;
  const int scol = (l & 3) * 8;
  const bf16* gA = A + (size_t)(mbase + (BM == 128 ? w * 32 : w * 16) + srow) * K + scol;
  const bf16* gB = Bt + (size_t)(nbase + (BN == 128 ? w * 32 : w * 16) + srow) * K + scol;

#define GSTAGE(bufi, t)                                                      \
  {                                                                          \
    const int k0_ = (t) * 32;                                                \
    if constexpr (BM == 128) {                                               \
      gload16(gA + k0_, &sA[bufi][w * 1024]);                                \
      gload16(gA + k0_ + (size_t)16 * K, &sA[bufi][w * 1024 + 512]);         \
    } else {                                                                 \
      gload16(gA + k0_, &sA[bufi][w * 512]);                                 \
    }                                                                        \
    if constexpr (BN == 128) {                                               \
      gload16(gB + k0_, &sB[bufi][w * 1024]);                                \
      gload16(gB + k0_ + (size_t)16 * K, &sB[bufi][w * 1024 + 512]);         \
    } else {                                                                 \
      gload16(gB + k0_, &sB[bufi][w * 512]);                                 \
    }                                                                        \
  }

  const int nt = K >> 5;
  GSTAGE(0, 0);
  for (int t = 0; t < nt; ++t) {
    const int cur = t & 1;
    if (t + 1 < nt) {
      GSTAGE(cur ^ 1, t + 1);
      if constexpr (LOADS == 4)      asm volatile("s_waitcnt vmcnt(4)" ::: "memory");
      else if constexpr (LOADS == 3) asm volatile("s_waitcnt vmcnt(3)" ::: "memory");
      else                           asm volatile("s_waitcnt vmcnt(2)" ::: "memory");
    } else {
      asm volatile("s_waitcnt vmcnt(0)" ::: "memory");
    }
    __builtin_amdgcn_s_barrier();        // buf[cur] complete for all waves
    __builtin_amdgcn_sched_barrier(0);

    short8 a[MI], bb[NI];
#pragma unroll
    for (int mi = 0; mi < MI; ++mi)
      a[mi] = *(const short8*)&sA[cur][(wm + mi * 16 + lr) * 32 + lg * 8];
#pragma unroll
    for (int ni = 0; ni < NI; ++ni)
      bb[ni] = *(const short8*)&sB[cur][(wn + ni * 16 + lr) * 32 + lg * 8];
#pragma unroll
    for (int mi = 0; mi < MI; ++mi)
#pragma unroll
      for (int ni = 0; ni < NI; ++ni)
        acc[mi][ni] = __builtin_amdgcn_mfma_f32_16x16x32_bf16(a[mi], bb[ni], acc[mi][ni], 0, 0, 0);

    __builtin_amdgcn_s_barrier();        // all waves done reading buf[cur]
    __builtin_amdgcn_sched_barrier(0);
  }
#undef GSTAGE

  const int row0 = mbase + wm + lg * 4;
  const int col0 = nbase + wn + lr;
#pragma unroll
  for (int mi = 0; mi < MI; ++mi) {
#pragma unroll
    for (int ni = 0; ni < NI; ++ni) {
      const int c = col0 + ni * 16;
#pragma unroll
      for (int i = 0; i < 4; ++i) {
        const int r = row0 + mi * 16 + i;
        float v = acc[mi][ni][i];
        if constexpr (EPI == 0) {
          if (c < 1536) {
            float scv = (c < DMODEL) ? QSCALE : 1.0f;  // Q pre-scaled into exp2 domain
            ob[(size_t)r * 1536 + c] = __float2bfloat16(v * scv);
          } else {
            int within = c - 1536;
            int hh = within >> 6, kk = within & 63;
            int bidx = r >> 11, sq = r & 2047;
            // permuted seq slot so V key-order matches packed-P column order
            int sqp = (sq & ~63) | ((sq & 15) << 2) | ((sq >> 4) & 3);
            vt[(((size_t)bidx * NHEAD + hh) * DHEAD + kk) * SEQ + sqp] = __float2bfloat16(v);
          }
        } else if constexpr (EPI == 1) {
          of[(size_t)r * DMODEL + c] = add[(size_t)r * DMODEL + c] + v;
        } else if constexpr (EPI == 2) {
          float xx = v + bias[c];
          float ge = 0.5f * xx * (1.0f + erff(xx * 0.70710678118f));
          ob[(size_t)r * HID + c] = __float2bfloat16(ge);
        } else {
          of[(size_t)r * DMODEL + c] = add[(size_t)r * DMODEL + c] + v + bias[c];
        }
      }
    }
  }
}

// ---------------- flash attention (causal), v3 ----------------
// QBLK=64 (4 waves x 16 rows), KBLK=64, double-buffered K/V, XOR-swizzled LDS,
// DPP softmax reductions, packed b64 P-writes (key-permuted, V matches).
__global__ __launch_bounds__(256) void attn_k(const bf16* __restrict__ qk,
                                              const bf16* __restrict__ vt,
                                              bf16* __restrict__ o) {
  __shared__ bf16 sK[2][64 * 64];   // [key][dk], XOR-swizzled 16B chunks
  __shared__ bf16 sV[2][64 * 64];   // [dk][key'], XOR-swizzled (key' = permuted)
  __shared__ bf16 sP[64 * 64];      // [qrow][key'], XOR-swizzled, wave-private rows

  const int d = blockIdx.x;                 // 0..767
  const int bh = d % 24;
  const int rank = d / 24;                  // 0..31
  const int qt = (rank * 21) & 31;          // balance work across dispatch order
  const int b = bh / NHEAD, h = bh - b * NHEAD;
  const int qbase = qt * 64;
  const int tid = threadIdx.x, w = tid >> 6, l = tid & 63;
  const int lr = l & 15, lg = l >> 4;

  short8 q[2];
#pragma unroll
  for (int kk = 0; kk < 2; ++kk)
    q[kk] = *(const short8*)&qk[(size_t)(b * SEQ + qbase + w * 16 + lr) * 1536 + h * DHEAD + kk * 32 + lg * 8];

  f32x4 oa[4];
  float mst[4], lst[4];
#pragma unroll
  for (int i = 0; i < 4; ++i) { oa[i] = (f32x4)0.0f; mst[i] = -1e30f; lst[i] = 0.0f; }

  const int srow3 = l >> 3;
  const int csrc = (l & 7) ^ srow3;         // pre-swizzled 16B chunk (both-sides rule)
  const bf16* gKb = qk + ((size_t)(b * SEQ) + w * 16 + srow3) * 1536 + DMODEL + h * DHEAD + csrc * 8;
  const bf16* gVb = vt + ((size_t)bh * DHEAD + w * 16 + srow3) * SEQ + csrc * 8;

  int rowb[4], cswz[2];
#pragma unroll
  for (int ni = 0; ni < 4; ++ni) rowb[ni] = (ni * 16 + lr) * 64;
#pragma unroll
  for (int kk = 0; kk < 2; ++kk) cswz[kk] = (((kk * 4 + lg) ^ (lr & 7)) << 3);
  const int prow = (w * 16 + lr) * 64;      // read row base (elements)

#define STAGE(buf, t)                                                              \
  {                                                                                \
    const int kb_ = (t) * 64;                                                      \
    gload16(gKb + (size_t)kb_ * 1536,        &sK[buf][(w * 16) * 64]);             \
    gload16(gKb + (size_t)(kb_ + 8) * 1536,  &sK[buf][(w * 16 + 8) * 64]);         \
    gload16(gVb + kb_,                       &sV[buf][(w * 16) * 64]);             \
    gload16(gVb + kb_ + (size_t)8 * SEQ,     &sV[buf][(w * 16 + 8) * 64]);         \
  }

  STAGE(0, 0);

  for (int t = 0; t <= qt; ++t) {
    const int cur = t & 1;
    const int kb = t * 64;
    if (t < qt) {
      STAGE(cur ^ 1, t + 1);
      asm volatile("s_waitcnt vmcnt(4)" ::: "memory");
    } else {
      asm volatile("s_waitcnt vmcnt(0)" ::: "memory");
    }
    __builtin_amdgcn_s_barrier();
    __builtin_amdgcn_sched_barrier(0);

    const bf16* sKc = sK[cur];
    const bf16* sVc = sV[cur];

    // ---- S = Q K^T (exp2 domain) ----
    f32x4 sc[4];
    __builtin_amdgcn_s_setprio(1);
#pragma unroll
    for (int ni = 0; ni < 4; ++ni) {
      sc[ni] = (f32x4)0.0f;
#pragma unroll
      for (int kk = 0; kk < 2; ++kk) {
        short8 kf = *(const short8*)&sKc[rowb[ni] + cswz[kk]];
        sc[ni] = __builtin_amdgcn_mfma_f32_16x16x32_bf16(q[kk], kf, sc[ni], 0, 0, 0);
      }
    }
    __builtin_amdgcn_s_setprio(0);

    // ---- mask + online softmax (DPP reductions, deferred sum) ----
    const bool need_mask = (kb + 63) > (qbase + w * 16);   // wave-uniform
    const int qrow0 = qbase + w * 16 + lg * 4;
#pragma unroll
    for (int i = 0; i < 4; ++i) {
      float v0 = sc[0][i], v1 = sc[1][i], v2 = sc[2][i], v3 = sc[3][i];
      if (need_mask) {
        const int qg = qrow0 + i;
        v0 = (kb + lr      > qg) ? -1e30f : v0;
        v1 = (kb + 16 + lr > qg) ? -1e30f : v1;
        v2 = (kb + 32 + lr > qg) ? -1e30f : v2;
        v3 = (kb + 48 + lr > qg) ? -1e30f : v3;
      }
      float tmax = fmaxf(fmaxf(v0, v1), fmaxf(v2, v3));
      tmax = red_max16(tmax);
      const float mn = fmaxf(mst[i], tmax);
      const float scale = exp2f(mst[i] - mn);
      mst[i] = mn;
      float p0 = exp2f(v0 - mn), p1 = exp2f(v1 - mn);
      float p2 = exp2f(v2 - mn), p3 = exp2f(v3 - mn);
      lst[i] = lst[i] * scale + ((p0 + p1) + (p2 + p3));   // per-lane partial
      int r0, r1;
      asm("v_cvt_pk_bf16_f32 %0, %1, %2" : "=v"(r0) : "v"(p0), "v"(p1));
      asm("v_cvt_pk_bf16_f32 %0, %1, %2" : "=v"(r1) : "v"(p2), "v"(p3));
      const int rrow = w * 16 + lg * 4 + i;
      *(i32x2*)((char*)sP + rrow * 128 + ((lr * 8) ^ ((rrow & 7) << 4))) = (i32x2){r0, r1};
#pragma unroll
      for (int nk = 0; nk < 4; ++nk) oa[nk][i] *= scale;
    }
    asm volatile("s_waitcnt lgkmcnt(0)" ::: "memory");
    __builtin_amdgcn_sched_barrier(0);

    // ---- PV (keys in permuted order on both P and V) ----
    short8 pf0 = *(const short8*)&sP[prow + cswz[0]];
    short8 pf1 = *(const short8*)&sP[prow + cswz[1]];
    __builtin_amdgcn_s_setprio(1);
#pragma unroll
    for (int nk = 0; nk < 4; ++nk) {
      short8 vf0 = *(const short8*)&sVc[rowb[nk] + cswz[0]];
      short8 vf1 = *(const short8*)&sVc[rowb[nk] + cswz[1]];
      oa[nk] = __builtin_amdgcn_mfma_f32_16x16x32_bf16(pf0, vf0, oa[nk], 0, 0, 0);
      oa[nk] = __builtin_amdgcn_mfma_f32_16x16x32_bf16(pf1, vf1, oa[nk], 0, 0, 0);
    }
    __builtin_amdgcn_s_setprio(0);
    __builtin_amdgcn_s_barrier();
    __builtin_amdgcn_sched_barrier(0);
  }
#undef STAGE

  // ---- epilogue: final sum reduce + O / l ----
#pragma unroll
  for (int i = 0; i < 4; ++i) lst[i] = red_add16(lst[i]);
#pragma unroll
  for (int i = 0; i < 4; ++i) {
    const float rl = __builtin_amdgcn_rcpf(lst[i]);
#pragma unroll
    for (int nk = 0; nk < 4; ++nk) {
      int row = qbase + w * 16 + lg * 4 + i;
      int col = h * DHEAD + nk * 16 + lr;
      o[(size_t)(b * SEQ + row) * DMODEL + col] = __float2bfloat16(oa[nk][i] * rl);
    }
  }
}

// ---------------- launch ----------------
extern "C" void kernel_launch(void* const* d_in, const int* in_sizes, int n_in,
                              void* d_out, int out_size, void* d_ws, size_t ws_size,
                              hipStream_t stream) {
  (void)in_sizes; (void)n_in; (void)out_size; (void)ws_size;
  const float* x   = (const float*)d_in[0];
  const float* Wq  = (const float*)d_in[1];
  const float* Wk  = (const float*)d_in[2];
  const float* Wv  = (const float*)d_in[3];
  const float* Wo  = (const float*)d_in[4];
  const float* W1  = (const float*)d_in[5];
  const float* b1  = (const float*)d_in[6];
  const float* W2  = (const float*)d_in[7];
  const float* b2  = (const float*)d_in[8];
  const float* g1  = (const float*)d_in[9];
  const float* be1 = (const float*)d_in[10];
  const float* g2  = (const float*)d_in[11];
  const float* be2 = (const float*)d_in[12];
  float* out = (float*)d_out;

  char* p = (char*)d_ws;
  bf16* WqkvT = (bf16*)p; p += (size_t)2304 * 768 * 2;
  bf16* WoT   = (bf16*)p; p += (size_t)768 * 768 * 2;
  bf16* W1T   = (bf16*)p; p += (size_t)3072 * 768 * 2;
  bf16* W2T   = (bf16*)p; p += (size_t)768 * 3072 * 2;
  bf16* h1    = (bf16*)p; p += (size_t)MROWS * DMODEL * 2;
  char* alias0 = p;                                   // U aliases QK+Vt+O (dead by then)
  bf16* QK    = (bf16*)p; p += (size_t)MROWS * 1536 * 2;
  bf16* Vt    = (bf16*)p; p += (size_t)24 * DHEAD * SEQ * 2;
  bf16* O     = (bf16*)p; p += (size_t)MROWS * DMODEL * 2;
  float* y    = (float*)p; p += (size_t)MROWS * DMODEL * 4;
  bf16* h2    = (bf16*)p; p += (size_t)MROWS * DMODEL * 2;
  bf16* U     = (bf16*)alias0;                        // [4096][3072] bf16

  dim3 blk(256);
  cvt_qkv_k<<<(2304 * 768) / 256, blk, 0, stream>>>(Wq, Wk, Wv, WqkvT);
  cvt_t_k<<<(768 * 768) / 256, blk, 0, stream>>>(Wo, WoT, 768, 768);
  cvt_t_k<<<(768 * 3072) / 256, blk, 0, stream>>>(W1, W1T, 768, 3072);
  cvt_t_k<<<(3072 * 768) / 256, blk, 0, stream>>>(W2, W2T, 3072, 768);
  ln_k<<<MROWS, blk, 0, stream>>>(x, g1, be1, h1);
  gemm_bt<0, 128, 128><<<dim3(18, 32), blk, 0, stream>>>(h1, WqkvT, 768, QK, nullptr, nullptr, nullptr, Vt);
  attn_k<<<768, blk, 0, stream>>>(QK, Vt, O);
  gemm_bt<1, 64, 64><<<dim3(12, 64), blk, 0, stream>>>(O, WoT, 768, nullptr, y, x, nullptr, nullptr);
  ln_k<<<MROWS, blk, 0, stream>>>(y, g2, be2, h2);
  gemm_bt<2, 128, 128><<<dim3(24, 32), blk, 0, stream>>>(h2, W1T, 768, U, nullptr, nullptr, b1, nullptr);
  gemm_bt<3, 64, 64><<<dim3(12, 64), blk, 0, stream>>>(U, W2T, 3072, nullptr, out, y, b2, nullptr);
}

// Round 5
// 251.705 us; speedup vs baseline: 1.4215x; 1.0269x over previous
//
#include <hip/hip_runtime.h>
#include <hip/hip_bf16.h>
#include <cstdint>
#include <cstddef>

using bf16 = __hip_bfloat16;
typedef __attribute__((ext_vector_type(8))) short short8;
typedef __attribute__((ext_vector_type(4))) float f32x4;
typedef __attribute__((ext_vector_type(2))) int i32x2;

#define DEV static __device__ __forceinline__

// B=2, S=2048, D=768, H=12, DK=64, HID=3072, M = B*S = 4096
#define MROWS 4096
#define SEQ   2048
#define DMODEL 768
#define NHEAD 12
#define DHEAD 64
#define HID   3072
// 0.125 * log2(e): QK^T lands in exp2 domain
#define QSCALE 0.1803368801111204f

DEV void gload16(const void* g, void* l) {
  __builtin_amdgcn_global_load_lds((const __attribute__((address_space(1))) void*)g,
                                   (__attribute__((address_space(3))) void*)l, 16, 0, 0);
}

template <int CTRL>
DEV float dppf(float x) {
  return __builtin_bit_cast(float,
      __builtin_amdgcn_mov_dpp(__builtin_bit_cast(int, x), CTRL, 0xF, 0xF, true));
}
// all-reduce over the 16 lanes of a DPP row (our lr dimension)
DEV float red_max16(float x) {
  x = fmaxf(x, dppf<0xB1>(x));   // quad_perm [1,0,3,2]
  x = fmaxf(x, dppf<0x4E>(x));   // quad_perm [2,3,0,1]
  x = fmaxf(x, dppf<0x141>(x));  // row_half_mirror
  x = fmaxf(x, dppf<0x140>(x));  // row_mirror
  return x;
}
DEV float red_add16(float x) {
  x += dppf<0xB1>(x);
  x += dppf<0x4E>(x);
  x += dppf<0x141>(x);
  x += dppf<0x140>(x);
  return x;
}

// ---------------- weight conversion ----------------
__global__ __launch_bounds__(256) void cvt_qkv_k(const float* __restrict__ Wq,
                                                 const float* __restrict__ Wk,
                                                 const float* __restrict__ Wv,
                                                 bf16* __restrict__ out) {
  int idx = blockIdx.x * 256 + threadIdx.x;          // [0, 2304*768)
  int n = idx / DMODEL, d = idx - n * DMODEL;
  int proj = n / DMODEL;
  int within = n - proj * DMODEL;
  int hh = within >> 6, k = within & 63;
  const float* W = (proj == 0) ? Wq : (proj == 1 ? Wk : Wv);
  out[idx] = __float2bfloat16(W[((size_t)hh * DMODEL + d) * DHEAD + k]);
}

// W[R][C] row-major -> out[C][R] bf16
__global__ __launch_bounds__(256) void cvt_t_k(const float* __restrict__ W,
                                               bf16* __restrict__ out, int R, int C) {
  int idx = blockIdx.x * 256 + threadIdx.x;
  int c = idx / R, r = idx - c * R;
  out[idx] = __float2bfloat16(W[(size_t)r * C + c]);
}

// ---------------- layernorm (row of 768) ----------------
__global__ __launch_bounds__(256) void ln_k(const float* __restrict__ in,
                                            const float* __restrict__ gam,
                                            const float* __restrict__ bet,
                                            bf16* __restrict__ out) {
  int r = blockIdx.x;
  int tid = threadIdx.x;
  const float* p = in + (size_t)r * DMODEL;
  float v0 = p[tid], v1 = p[tid + 256], v2 = p[tid + 512];
  float s = v0 + v1 + v2;
  float ss = v0 * v0 + v1 * v1 + v2 * v2;
#pragma unroll
  for (int off = 1; off < 64; off <<= 1) {
    s += __shfl_xor(s, off);
    ss += __shfl_xor(ss, off);
  }
  __shared__ float rs[4], rss[4];
  int w = tid >> 6, l = tid & 63;
  if (l == 0) { rs[w] = s; rss[w] = ss; }
  __syncthreads();
  s = rs[0] + rs[1] + rs[2] + rs[3];
  ss = rss[0] + rss[1] + rss[2] + rss[3];
  float mean = s * (1.0f / 768.0f);
  float var = ss * (1.0f / 768.0f) - mean * mean;
  float inv = rsqrtf(var + 1e-5f);
  bf16* o = out + (size_t)r * DMODEL;
  o[tid]       = __float2bfloat16((v0 - mean) * inv * gam[tid] + bet[tid]);
  o[tid + 256] = __float2bfloat16((v1 - mean) * inv * gam[tid + 256] + bet[tid + 256]);
  o[tid + 512] = __float2bfloat16((v2 - mean) * inv * gam[tid + 512] + bet[tid + 512]);
}

// ---------------- GEMM: C[M][N] = A[M][K] * Bt[N][K]^T ----------------
// Tile BM x BN, BK=32, double-buffered LDS, counted vmcnt, raw barriers,
// XOR-swizzled LDS (pre-swizzled global source; linear gload_lds dest).
template <int EPI, int BM, int BN>
__global__ __launch_bounds__(256) void gemm_bt(const bf16* __restrict__ A,
                                               const bf16* __restrict__ Bt, int K,
                                               bf16* __restrict__ ob,
                                               float* __restrict__ of,
                                               const float* __restrict__ add,
                                               const float* __restrict__ bias,
                                               bf16* __restrict__ vt) {
  __shared__ bf16 sA[2][BM * 32];
  __shared__ bf16 sB[2][BN * 32];
  constexpr int MI = BM / 32;
  constexpr int NI = BN / 32;
  constexpr int LOADS = (BM == 128 ? 2 : 1) + (BN == 128 ? 2 : 1);
  const int tid = threadIdx.x;
  const int w = tid >> 6, l = tid & 63;
  const int lr = l & 15, lg = l >> 4;
  const int mbase = blockIdx.y * BM, nbase = blockIdx.x * BN;
  const int wm = (w >> 1) * (BM / 2), wn = (w & 1) * (BN / 2);

  f32x4 acc[MI][NI];
#pragma unroll
  for (int i = 0; i < MI; ++i)
#pragma unroll
    for (int j = 0; j < NI; ++j) acc[i][j] = (f32x4)0.0f;

  // staging: lane l loads row (l>>2), 16B-chunk ((l&3) ^ ((l>>3)&3))  [swizzle src]
  const int srow = l >> 2;
  const int scol = ((l & 3) ^ ((l >> 3) & 3)) * 8;
  const bf16* gA = A + (size_t)(mbase + (BM == 128 ? w * 32 : w * 16) + srow) * K + scol;
  const bf16* gB = Bt + (size_t)(nbase + (BN == 128 ? w * 32 : w * 16) + srow) * K + scol;
  // fragment read: chunk lg ^ ((lr>>1)&3) of each row
  const int foff = (lg ^ ((lr >> 1) & 3)) * 8;

#define GSTAGE(bufi, t)                                                      \
  {                                                                          \
    const int k0_ = (t) * 32;                                                \
    if constexpr (BM == 128) {                                               \
      gload16(gA + k0_, &sA[bufi][w * 1024]);                                \
      gload16(gA + k0_ + (size_t)16 * K, &sA[bufi][w * 1024 + 512]);         \
    } else {                                                                 \
      gload16(gA + k0_, &sA[bufi][w * 512]);                                 \
    }                                                                        \
    if constexpr (BN == 128) {                                               \
      gload16(gB + k0_, &sB[bufi][w * 1024]);                                \
      gload16(gB + k0_ + (size_t)16 * K, &sB[bufi][w * 1024 + 512]);         \
    } else {                                                                 \
      gload16(gB + k0_, &sB[bufi][w * 512]);                                 \
    }                                                                        \
  }

  const int nt = K >> 5;
  GSTAGE(0, 0);
  for (int t = 0; t < nt; ++t) {
    const int cur = t & 1;
    if (t + 1 < nt) {
      GSTAGE(cur ^ 1, t + 1);
      if constexpr (LOADS == 4)      asm volatile("s_waitcnt vmcnt(4)" ::: "memory");
      else if constexpr (LOADS == 3) asm volatile("s_waitcnt vmcnt(3)" ::: "memory");
      else                           asm volatile("s_waitcnt vmcnt(2)" ::: "memory");
    } else {
      asm volatile("s_waitcnt vmcnt(0)" ::: "memory");
    }
    __builtin_amdgcn_s_barrier();        // buf[cur] complete for all waves
    __builtin_amdgcn_sched_barrier(0);

    short8 a[MI], bb[NI];
#pragma unroll
    for (int mi = 0; mi < MI; ++mi)
      a[mi] = *(const short8*)&sA[cur][(wm + mi * 16 + lr) * 32 + foff];
#pragma unroll
    for (int ni = 0; ni < NI; ++ni)
      bb[ni] = *(const short8*)&sB[cur][(wn + ni * 16 + lr) * 32 + foff];
#pragma unroll
    for (int mi = 0; mi < MI; ++mi)
#pragma unroll
      for (int ni = 0; ni < NI; ++ni)
        acc[mi][ni] = __builtin_amdgcn_mfma_f32_16x16x32_bf16(a[mi], bb[ni], acc[mi][ni], 0, 0, 0);

    __builtin_amdgcn_s_barrier();        // all waves done reading buf[cur]
    __builtin_amdgcn_sched_barrier(0);
  }
#undef GSTAGE

  const int row0 = mbase + wm + lg * 4;
  const int col0 = nbase + wn + lr;
#pragma unroll
  for (int mi = 0; mi < MI; ++mi) {
#pragma unroll
    for (int ni = 0; ni < NI; ++ni) {
      const int c = col0 + ni * 16;
#pragma unroll
      for (int i = 0; i < 4; ++i) {
        const int r = row0 + mi * 16 + i;
        float v = acc[mi][ni][i];
        if constexpr (EPI == 0) {
          if (c < 1536) {
            float scv = (c < DMODEL) ? QSCALE : 1.0f;  // Q pre-scaled into exp2 domain
            ob[(size_t)r * 1536 + c] = __float2bfloat16(v * scv);
          } else {
            int within = c - 1536;
            int hh = within >> 6, kk = within & 63;
            int bidx = r >> 11, sq = r & 2047;
            // permuted seq slot so V key-order matches packed-P column order
            int sqp = (sq & ~63) | ((sq & 15) << 2) | ((sq >> 4) & 3);
            vt[(((size_t)bidx * NHEAD + hh) * DHEAD + kk) * SEQ + sqp] = __float2bfloat16(v);
          }
        } else if constexpr (EPI == 1) {
          of[(size_t)r * DMODEL + c] = add[(size_t)r * DMODEL + c] + v;
        } else if constexpr (EPI == 2) {
          float xx = v + bias[c];
          float ge = 0.5f * xx * (1.0f + erff(xx * 0.70710678118f));
          ob[(size_t)r * HID + c] = __float2bfloat16(ge);
        } else {
          of[(size_t)r * DMODEL + c] = add[(size_t)r * DMODEL + c] + v + bias[c];
        }
      }
    }
  }
}

// ---------------- flash attention (causal), v4 ----------------
// QBLK=64 (4 waves x 16 rows), KBLK=64, double-buffered K/V, XOR-swizzled LDS,
// DPP softmax reductions, packed b64 P-writes, LPT dispatch, defer-max.
__global__ __launch_bounds__(256) void attn_k(const bf16* __restrict__ qk,
                                              const bf16* __restrict__ vt,
                                              bf16* __restrict__ o) {
  __shared__ bf16 sK[2][64 * 64];   // [key][dk], XOR-swizzled 16B chunks
  __shared__ bf16 sV[2][64 * 64];   // [dk][key'], XOR-swizzled (key' = permuted)
  __shared__ bf16 sP[64 * 64];      // [qrow][key'], XOR-swizzled, wave-private rows

  const int d = blockIdx.x;                 // 0..767
  const int bh = d % 24;
  const int qt = 31 - d / 24;               // LPT: fattest blocks dispatch first
  const int b = bh / NHEAD, h = bh - b * NHEAD;
  const int qbase = qt * 64;
  const int tid = threadIdx.x, w = tid >> 6, l = tid & 63;
  const int lr = l & 15, lg = l >> 4;

  short8 q[2];
#pragma unroll
  for (int kk = 0; kk < 2; ++kk)
    q[kk] = *(const short8*)&qk[(size_t)(b * SEQ + qbase + w * 16 + lr) * 1536 + h * DHEAD + kk * 32 + lg * 8];

  f32x4 oa[4];
  float mst[4], lst[4];
#pragma unroll
  for (int i = 0; i < 4; ++i) { oa[i] = (f32x4)0.0f; mst[i] = -1e30f; lst[i] = 0.0f; }

  const int srow3 = l >> 3;
  const int csrc = (l & 7) ^ srow3;         // pre-swizzled 16B chunk (both-sides rule)
  const bf16* gKb = qk + ((size_t)(b * SEQ) + w * 16 + srow3) * 1536 + DMODEL + h * DHEAD + csrc * 8;
  const bf16* gVb = vt + ((size_t)bh * DHEAD + w * 16 + srow3) * SEQ + csrc * 8;

  int rowb[4], cswz[2];
#pragma unroll
  for (int ni = 0; ni < 4; ++ni) rowb[ni] = (ni * 16 + lr) * 64;
#pragma unroll
  for (int kk = 0; kk < 2; ++kk) cswz[kk] = (((kk * 4 + lg) ^ (lr & 7)) << 3);
  const int prow = (w * 16 + lr) * 64;      // read row base (elements)

#define STAGE(buf, t)                                                              \
  {                                                                                \
    const int kb_ = (t) * 64;                                                      \
    gload16(gKb + (size_t)kb_ * 1536,        &sK[buf][(w * 16) * 64]);             \
    gload16(gKb + (size_t)(kb_ + 8) * 1536,  &sK[buf][(w * 16 + 8) * 64]);         \
    gload16(gVb + kb_,                       &sV[buf][(w * 16) * 64]);             \
    gload16(gVb + kb_ + (size_t)8 * SEQ,     &sV[buf][(w * 16 + 8) * 64]);         \
  }

  STAGE(0, 0);

  for (int t = 0; t <= qt; ++t) {
    const int cur = t & 1;
    const int kb = t * 64;
    if (t < qt) {
      STAGE(cur ^ 1, t + 1);
      asm volatile("s_waitcnt vmcnt(4)" ::: "memory");
    } else {
      asm volatile("s_waitcnt vmcnt(0)" ::: "memory");
    }
    __builtin_amdgcn_s_barrier();
    __builtin_amdgcn_sched_barrier(0);

    const bf16* sKc = sK[cur];
    const bf16* sVc = sV[cur];

    // ---- S = Q K^T (exp2 domain) ----
    f32x4 sc[4];
    __builtin_amdgcn_s_setprio(1);
#pragma unroll
    for (int ni = 0; ni < 4; ++ni) {
      sc[ni] = (f32x4)0.0f;
#pragma unroll
      for (int kk = 0; kk < 2; ++kk) {
        short8 kf = *(const short8*)&sKc[rowb[ni] + cswz[kk]];
        sc[ni] = __builtin_amdgcn_mfma_f32_16x16x32_bf16(q[kk], kf, sc[ni], 0, 0, 0);
      }
    }
    __builtin_amdgcn_s_setprio(0);

    // ---- mask + row max ----
    const bool need_mask = (kb + 63) > (qbase + w * 16);   // wave-uniform
    const int qrow0 = qbase + w * 16 + lg * 4;
    float tm[4];
#pragma unroll
    for (int i = 0; i < 4; ++i) {
      float v0 = sc[0][i], v1 = sc[1][i], v2 = sc[2][i], v3 = sc[3][i];
      if (need_mask) {
        const int qg = qrow0 + i;
        v0 = (kb + lr      > qg) ? -1e30f : v0;
        v1 = (kb + 16 + lr > qg) ? -1e30f : v1;
        v2 = (kb + 32 + lr > qg) ? -1e30f : v2;
        v3 = (kb + 48 + lr > qg) ? -1e30f : v3;
        sc[0][i] = v0; sc[1][i] = v1; sc[2][i] = v2; sc[3][i] = v3;
      }
      tm[i] = red_max16(fmaxf(fmaxf(v0, v1), fmaxf(v2, v3)));
    }

    // ---- defer-max (T13): rescale only when max grows > THR ----
    bool grow = (tm[0] > mst[0] + 12.0f) || (tm[1] > mst[1] + 12.0f) ||
                (tm[2] > mst[2] + 12.0f) || (tm[3] > mst[3] + 12.0f);
    if (__any((int)grow)) {
#pragma unroll
      for (int i = 0; i < 4; ++i) {
        const float mn = fmaxf(mst[i], tm[i]);
        const float scale = exp2f(mst[i] - mn);
        mst[i] = mn;
        lst[i] *= scale;
#pragma unroll
        for (int nk = 0; nk < 4; ++nk) oa[nk][i] *= scale;
      }
    }

    // ---- exp + pack + P write ----
#pragma unroll
    for (int i = 0; i < 4; ++i) {
      float p0 = exp2f(sc[0][i] - mst[i]), p1 = exp2f(sc[1][i] - mst[i]);
      float p2 = exp2f(sc[2][i] - mst[i]), p3 = exp2f(sc[3][i] - mst[i]);
      lst[i] += (p0 + p1) + (p2 + p3);   // per-lane partial
      int r0, r1;
      asm("v_cvt_pk_bf16_f32 %0, %1, %2" : "=v"(r0) : "v"(p0), "v"(p1));
      asm("v_cvt_pk_bf16_f32 %0, %1, %2" : "=v"(r1) : "v"(p2), "v"(p3));
      const int rrow = w * 16 + lg * 4 + i;
      *(i32x2*)((char*)sP + rrow * 128 + ((lr * 8) ^ ((rrow & 7) << 4))) = (i32x2){r0, r1};
    }
    asm volatile("s_waitcnt lgkmcnt(0)" ::: "memory");
    __builtin_amdgcn_sched_barrier(0);

    // ---- PV (keys in permuted order on both P and V) ----
    short8 pf0 = *(const short8*)&sP[prow + cswz[0]];
    short8 pf1 = *(const short8*)&sP[prow + cswz[1]];
    __builtin_amdgcn_s_setprio(1);
#pragma unroll
    for (int nk = 0; nk < 4; ++nk) {
      short8 vf0 = *(const short8*)&sVc[rowb[nk] + cswz[0]];
      short8 vf1 = *(const short8*)&sVc[rowb[nk] + cswz[1]];
      oa[nk] = __builtin_amdgcn_mfma_f32_16x16x32_bf16(pf0, vf0, oa[nk], 0, 0, 0);
      oa[nk] = __builtin_amdgcn_mfma_f32_16x16x32_bf16(pf1, vf1, oa[nk], 0, 0, 0);
    }
    __builtin_amdgcn_s_setprio(0);
    __builtin_amdgcn_s_barrier();
    __builtin_amdgcn_sched_barrier(0);
  }
#undef STAGE

  // ---- epilogue: final sum reduce + O / l ----
#pragma unroll
  for (int i = 0; i < 4; ++i) lst[i] = red_add16(lst[i]);
#pragma unroll
  for (int i = 0; i < 4; ++i) {
    const float rl = __builtin_amdgcn_rcpf(lst[i]);
#pragma unroll
    for (int nk = 0; nk < 4; ++nk) {
      int row = qbase + w * 16 + lg * 4 + i;
      int col = h * DHEAD + nk * 16 + lr;
      o[(size_t)(b * SEQ + row) * DMODEL + col] = __float2bfloat16(oa[nk][i] * rl);
    }
  }
}

// ---------------- launch ----------------
extern "C" void kernel_launch(void* const* d_in, const int* in_sizes, int n_in,
                              void* d_out, int out_size, void* d_ws, size_t ws_size,
                              hipStream_t stream) {
  (void)in_sizes; (void)n_in; (void)out_size; (void)ws_size;
  const float* x   = (const float*)d_in[0];
  const float* Wq  = (const float*)d_in[1];
  const float* Wk  = (const float*)d_in[2];
  const float* Wv  = (const float*)d_in[3];
  const float* Wo  = (const float*)d_in[4];
  const float* W1  = (const float*)d_in[5];
  const float* b1  = (const float*)d_in[6];
  const float* W2  = (const float*)d_in[7];
  const float* b2  = (const float*)d_in[8];
  const float* g1  = (const float*)d_in[9];
  const float* be1 = (const float*)d_in[10];
  const float* g2  = (const float*)d_in[11];
  const float* be2 = (const float*)d_in[12];
  float* out = (float*)d_out;

  char* p = (char*)d_ws;
  bf16* WqkvT = (bf16*)p; p += (size_t)2304 * 768 * 2;
  bf16* WoT   = (bf16*)p; p += (size_t)768 * 768 * 2;
  bf16* W1T   = (bf16*)p; p += (size_t)3072 * 768 * 2;
  bf16* W2T   = (bf16*)p; p += (size_t)768 * 3072 * 2;
  bf16* h1    = (bf16*)p; p += (size_t)MROWS * DMODEL * 2;
  char* alias0 = p;                                   // U aliases QK+Vt+O (dead by then)
  bf16* QK    = (bf16*)p; p += (size_t)MROWS * 1536 * 2;
  bf16* Vt    = (bf16*)p; p += (size_t)24 * DHEAD * SEQ * 2;
  bf16* O     = (bf16*)p; p += (size_t)MROWS * DMODEL * 2;
  float* y    = (float*)p; p += (size_t)MROWS * DMODEL * 4;
  bf16* h2    = (bf16*)p; p += (size_t)MROWS * DMODEL * 2;
  bf16* U     = (bf16*)alias0;                        // [4096][3072] bf16

  dim3 blk(256);
  cvt_qkv_k<<<(2304 * 768) / 256, blk, 0, stream>>>(Wq, Wk, Wv, WqkvT);
  cvt_t_k<<<(768 * 768) / 256, blk, 0, stream>>>(Wo, WoT, 768, 768);
  cvt_t_k<<<(768 * 3072) / 256, blk, 0, stream>>>(W1, W1T, 768, 3072);
  cvt_t_k<<<(3072 * 768) / 256, blk, 0, stream>>>(W2, W2T, 3072, 768);
  ln_k<<<MROWS, blk, 0, stream>>>(x, g1, be1, h1);
  gemm_bt<0, 128, 128><<<dim3(18, 32), blk, 0, stream>>>(h1, WqkvT, 768, QK, nullptr, nullptr, nullptr, Vt);
  attn_k<<<768, blk, 0, stream>>>(QK, Vt, O);
  gemm_bt<1, 64, 64><<<dim3(12, 64), blk, 0, stream>>>(O, WoT, 768, nullptr, y, x, nullptr, nullptr);
  ln_k<<<MROWS, blk, 0, stream>>>(y, g2, be2, h2);
  gemm_bt<2, 128, 128><<<dim3(24, 32), blk, 0, stream>>>(h2, W1T, 768, U, nullptr, nullptr, b1, nullptr);
  gemm_bt<3, 64, 64><<<dim3(12, 64), blk, 0, stream>>>(U, W2T, 3072, nullptr, out, y, b2, nullptr);
}